// Round 1
// baseline (892.325 us; speedup 1.0000x reference)
//
#include <hip/hip_runtime.h>
#include <stdint.h>

#define B_ 2
#define S_ 2048
#define D_ 1024
#define H_ 16
#define HD_ 64
#define DFF_ 4096
#define M_ 4096   // B*S

typedef float           f4_t  __attribute__((ext_vector_type(4)));
typedef unsigned int    ui4_t __attribute__((ext_vector_type(4)));
typedef unsigned short  us4_t __attribute__((ext_vector_type(4)));
typedef __bf16          bf8_t __attribute__((ext_vector_type(8)));

__device__ __forceinline__ float b2f(unsigned short u) {
    union { unsigned int u; float f; } v; v.u = ((unsigned int)u) << 16; return v.f;
}
__device__ __forceinline__ unsigned short f2b(float f) {
    union { float f; unsigned int u; } v; v.f = f;
    unsigned int u = v.u + 0x7fffu + ((v.u >> 16) & 1u);
    return (unsigned short)(u >> 16);
}

// ---------------- transpose fp32 [R][C] -> bf16 [C][R] ----------------
__global__ __launch_bounds__(256) void k_transpose(const float* __restrict__ in,
                                                   unsigned short* __restrict__ out,
                                                   int R, int C) {
    __shared__ float tile[32][33];
    const int bc = blockIdx.x * 32, br = blockIdx.y * 32;
    const int tx = threadIdx.x & 31, ty = threadIdx.x >> 5;
#pragma unroll
    for (int i = ty; i < 32; i += 8)
        tile[i][tx] = in[(size_t)(br + i) * C + bc + tx];
    __syncthreads();
#pragma unroll
    for (int i = ty; i < 32; i += 8)
        out[(size_t)(bc + i) * R + br + tx] = f2b(tile[tx][i]);
}

// ---------------- layernorm fp32 row(1024) -> bf16 ----------------
__global__ __launch_bounds__(256) void k_layernorm(const float* __restrict__ x,
                                                   const float* __restrict__ g,
                                                   const float* __restrict__ be,
                                                   unsigned short* __restrict__ out) {
    const int row = blockIdx.x;
    const int t = threadIdx.x;
    const float* xr = x + (size_t)row * D_;
    f4_t v = *(const f4_t*)&xr[t * 4];
    float s = v[0] + v[1] + v[2] + v[3];
#pragma unroll
    for (int o = 32; o >= 1; o >>= 1) s += __shfl_down(s, o);
    __shared__ float red[4];
    const int w = t >> 6, lane = t & 63;
    if (lane == 0) red[w] = s;
    __syncthreads();
    const float mean = (red[0] + red[1] + red[2] + red[3]) * (1.f / D_);
    f4_t d;
#pragma unroll
    for (int c = 0; c < 4; c++) d[c] = v[c] - mean;
    float ss = d[0]*d[0] + d[1]*d[1] + d[2]*d[2] + d[3]*d[3];
#pragma unroll
    for (int o = 32; o >= 1; o >>= 1) ss += __shfl_down(ss, o);
    __syncthreads();
    if (lane == 0) red[w] = ss;
    __syncthreads();
    const float var = (red[0] + red[1] + red[2] + red[3]) * (1.f / D_);
    const float rstd = rsqrtf(var + 1e-5f);
    f4_t gv = *(const f4_t*)&g[t * 4];
    f4_t bv = *(const f4_t*)&be[t * 4];
    us4_t o4;
#pragma unroll
    for (int c = 0; c < 4; c++) o4[c] = f2b(d[c] * rstd * gv[c] + bv[c]);
    *(us4_t*)&out[(size_t)row * D_ + t * 4] = o4;
}

// ---------------- bf16 MFMA GEMM: C[m][n] = sum_k A[m][k]*Bt[n][k] + bias ----------------
// 128x128 tile, BK=32, 4 waves (2x2), each wave 64x64 = 4x4 frags of 16x16x32 MFMA.
template<int RELU, int BF16OUT, int RESID>
__global__ __launch_bounds__(256) void k_gemm_bt(const unsigned short* __restrict__ A,
                                                 const unsigned short* __restrict__ Bt,
                                                 const float* __restrict__ bias,
                                                 const float* __restrict__ resid,
                                                 void* __restrict__ Cout,
                                                 int M, int N, int K) {
    __shared__ unsigned short As[128 * 32];
    __shared__ unsigned short Bs[128 * 32];
    const int tid = threadIdx.x;
    const int m0 = blockIdx.y * 128, n0 = blockIdx.x * 128;
    const int w = tid >> 6, lane = tid & 63;
    const int wr = w >> 1, wc = w & 1;
    const int lr = lane & 15, lg = lane >> 4;

    f4_t acc[4][4] = {};

    const int r1 = tid >> 2, q1 = tid & 3;  // staging: 512 16B-chunks, 2/thread
    const unsigned short* pA1 = A + (size_t)(m0 + r1) * K + q1 * 8;
    const unsigned short* pA2 = pA1 + (size_t)64 * K;
    const unsigned short* pB1 = Bt + (size_t)(n0 + r1) * K + q1 * 8;
    const unsigned short* pB2 = pB1 + (size_t)64 * K;
    const int la1 = r1 * 32 + q1 * 8, la2 = (r1 + 64) * 32 + q1 * 8;

    for (int k0 = 0; k0 < K; k0 += 32) {
        ui4_t a1 = *(const ui4_t*)(pA1 + k0);
        ui4_t a2 = *(const ui4_t*)(pA2 + k0);
        ui4_t b1 = *(const ui4_t*)(pB1 + k0);
        ui4_t b2 = *(const ui4_t*)(pB2 + k0);
        __syncthreads();
        *(ui4_t*)&As[la1] = a1;
        *(ui4_t*)&As[la2] = a2;
        *(ui4_t*)&Bs[la1] = b1;
        *(ui4_t*)&Bs[la2] = b2;
        __syncthreads();
        bf8_t af[4], bfr[4];
#pragma unroll
        for (int f = 0; f < 4; f++) {
            af[f]  = *(const bf8_t*)&As[(wr * 64 + f * 16 + lr) * 32 + lg * 8];
            bfr[f] = *(const bf8_t*)&Bs[(wc * 64 + f * 16 + lr) * 32 + lg * 8];
        }
#pragma unroll
        for (int mf = 0; mf < 4; mf++)
#pragma unroll
            for (int nf = 0; nf < 4; nf++)
                acc[mf][nf] = __builtin_amdgcn_mfma_f32_16x16x32_bf16(af[mf], bfr[nf], acc[mf][nf], 0, 0, 0);
    }

#pragma unroll
    for (int mf = 0; mf < 4; mf++) {
#pragma unroll
        for (int nf = 0; nf < 4; nf++) {
            const int n = n0 + wc * 64 + nf * 16 + lr;
            const float bv = bias[n];
#pragma unroll
            for (int j = 0; j < 4; j++) {
                const int m = m0 + wr * 64 + mf * 16 + lg * 4 + j;
                float val = acc[mf][nf][j] + bv;
                if (RESID) val += resid[(size_t)m * N + n];
                if (RELU) val = fmaxf(val, 0.f);
                if (BF16OUT) ((unsigned short*)Cout)[(size_t)m * N + n] = f2b(val);
                else         ((float*)Cout)[(size_t)m * N + n] = val;
            }
        }
    }
}

// ---------------- RoPE in-place on bf16 Q,K [B,S,H,64] ----------------
__global__ __launch_bounds__(256) void k_rope(unsigned short* __restrict__ Q,
                                              unsigned short* __restrict__ Kt) {
    const int idx = blockIdx.x * 256 + threadIdx.x;  // 2^21 pairs
    const int i = idx & 31;
    const int h = (idx >> 5) & 15;
    const int s = (idx >> 9) & 2047;
    const int b = idx >> 20;
    const float freq = exp2f(-(float)i * 0.4152410118609203f);  // 10000^(-i/32)
    const float ang = (float)s * freq;
    float sn, cs;
    sincosf(ang, &sn, &cs);
    const size_t base = ((size_t)(b * S_ + s)) * D_ + h * HD_ + i;
    {
        float a = b2f(Q[base]), c2 = b2f(Q[base + 32]);
        Q[base]      = f2b(a * cs - c2 * sn);
        Q[base + 32] = f2b(c2 * cs + a * sn);
    }
    {
        float a = b2f(Kt[base]), c2 = b2f(Kt[base + 32]);
        Kt[base]      = f2b(a * cs - c2 * sn);
        Kt[base + 32] = f2b(c2 * cs + a * sn);
    }
}

// ---------------- attention: full-row softmax, causal PV, -1e9 suffix-V term ----------------
#define QS_STR 68
#define KS_STR 72
#define PS_STR 68

__global__ __launch_bounds__(256) void k_attn(const unsigned short* __restrict__ Q,
                                              const unsigned short* __restrict__ K,
                                              const unsigned short* __restrict__ V,
                                              unsigned short* __restrict__ Out) {
    __shared__ float         Qs[64 * QS_STR];   // fp32 [q][d]
    __shared__ unsigned short Ks[64 * KS_STR];  // bf16 [k][d]
    __shared__ unsigned short Vt[64 * KS_STR];  // bf16 [d][k] (transposed)
    __shared__ float         Ps[64 * PS_STR];   // fp32 [q][k]

    const int qblk = blockIdx.x;       // 0..31
    const int bh = blockIdx.y;         // 0..31
    const int b = bh >> 4, h = bh & 15;
    const int q0 = qblk * 64;
    const int tid = threadIdx.x;
    const int tq = tid >> 4, tk = tid & 15;

    // load Q tile (bf16 -> fp32)
#pragma unroll
    for (int it = 0; it < 2; it++) {
        const int c = tid + it * 256;
        const int row = c >> 3, g = c & 7;
        const unsigned short* src = Q + ((size_t)(b * S_ + q0 + row)) * D_ + h * HD_ + g * 8;
        ui4_t raw = *(const ui4_t*)src;
#pragma unroll
        for (int e = 0; e < 4; e++) {
            unsigned int wrd = raw[e];
            union { unsigned int u; float f; } lo, hi;
            lo.u = wrd << 16;
            hi.u = wrd & 0xffff0000u;
            Qs[row * QS_STR + g * 8 + e * 2]     = lo.f;
            Qs[row * QS_STR + g * 8 + e * 2 + 1] = hi.f;
        }
    }

    float m_run[4], l_run[4], O[4][4], O2d[4][4], csacc[4];
#pragma unroll
    for (int i2 = 0; i2 < 4; i2++) {
        m_run[i2] = -1e30f; l_run[i2] = 0.f; csacc[i2] = 0.f;
#pragma unroll
        for (int jj = 0; jj < 4; jj++) { O[i2][jj] = 0.f; O2d[i2][jj] = 0.f; }
    }

    for (int kc = 0; kc < 32; kc++) {
        const int k0 = kc * 64;
        __syncthreads();  // prior-chunk LDS reads done (also publishes Qs on kc=0)
        // stage K tile [k][d] and V tile transposed [d][k]
#pragma unroll
        for (int it = 0; it < 2; it++) {
            const int c = tid + it * 256;
            const int row = c >> 3, g = c & 7;
            const size_t gbase = ((size_t)(b * S_ + k0 + row)) * D_ + h * HD_ + g * 8;
            *(ui4_t*)&Ks[row * KS_STR + g * 8] = *(const ui4_t*)(K + gbase);
            ui4_t vraw = *(const ui4_t*)(V + gbase);
            const unsigned short* vr = (const unsigned short*)&vraw;
#pragma unroll
            for (int e = 0; e < 8; e++)
                Vt[(g * 8 + e) * KS_STR + row] = vr[e];
        }
        __syncthreads();

        // scores: thread owns q rows tq*4+i, k cols tk+16*jj
        float sc[4][4];
#pragma unroll
        for (int i2 = 0; i2 < 4; i2++)
#pragma unroll
            for (int jj = 0; jj < 4; jj++) sc[i2][jj] = 0.f;

        for (int d4 = 0; d4 < 64; d4 += 4) {
            f4_t qv[4];
#pragma unroll
            for (int i2 = 0; i2 < 4; i2++)
                qv[i2] = *(const f4_t*)&Qs[(tq * 4 + i2) * QS_STR + d4];
#pragma unroll
            for (int jj = 0; jj < 4; jj++) {
                us4_t kr = *(const us4_t*)&Ks[(tk + 16 * jj) * KS_STR + d4];
                float kf[4];
#pragma unroll
                for (int dd = 0; dd < 4; dd++) kf[dd] = b2f(kr[dd]);
#pragma unroll
                for (int i2 = 0; i2 < 4; i2++)
#pragma unroll
                    for (int dd = 0; dd < 4; dd++)
                        sc[i2][jj] += qv[i2][dd] * kf[dd];
            }
        }

        // online softmax stats over full row (16-lane groups share a q row set)
#pragma unroll
        for (int i2 = 0; i2 < 4; i2++) {
#pragma unroll
            for (int jj = 0; jj < 4; jj++) sc[i2][jj] *= 0.125f;
            float mx = fmaxf(fmaxf(sc[i2][0], sc[i2][1]), fmaxf(sc[i2][2], sc[i2][3]));
#pragma unroll
            for (int o = 1; o < 16; o <<= 1) mx = fmaxf(mx, __shfl_xor(mx, o));
            const float mnew = fmaxf(m_run[i2], mx);
            const float scl = __expf(m_run[i2] - mnew);
            m_run[i2] = mnew;
            float csum = 0.f;
#pragma unroll
            for (int jj = 0; jj < 4; jj++) {
                const float p = __expf(sc[i2][jj] - mnew);
                sc[i2][jj] = p;
                csum += p;
            }
#pragma unroll
            for (int o = 1; o < 16; o <<= 1) csum += __shfl_xor(csum, o);
            l_run[i2] = l_run[i2] * scl + csum;
#pragma unroll
            for (int jj = 0; jj < 4; jj++) O[i2][jj] *= scl;
        }

        if (kc <= qblk) {
            // write P (masked at diagonal chunk: only k<=q kept)
#pragma unroll
            for (int i2 = 0; i2 < 4; i2++)
#pragma unroll
                for (int jj = 0; jj < 4; jj++) {
                    const int kl = tk + 16 * jj;
                    float p = sc[i2][jj];
                    if (kc == qblk && kl > tq * 4 + i2) p = 0.f;
                    Ps[(tq * 4 + i2) * PS_STR + kl] = p;
                }
        }
        __syncthreads();

        if (kc <= qblk) {
            for (int k4 = 0; k4 < 64; k4 += 4) {
                float vv[4][4];  // vv[c][jj] = V[k4+c][tk+16*jj]
#pragma unroll
                for (int jj = 0; jj < 4; jj++) {
                    us4_t vr = *(const us4_t*)&Vt[(tk + 16 * jj) * KS_STR + k4];
#pragma unroll
                    for (int c = 0; c < 4; c++) vv[c][jj] = b2f(vr[c]);
                }
#pragma unroll
                for (int i2 = 0; i2 < 4; i2++) {
                    f4_t p4 = *(const f4_t*)&Ps[(tq * 4 + i2) * PS_STR + k4];
#pragma unroll
                    for (int c = 0; c < 4; c++)
#pragma unroll
                        for (int jj = 0; jj < 4; jj++)
                            O[i2][jj] += p4[c] * vv[c][jj];
                }
                if (kc == qblk) {
#pragma unroll
                    for (int c = 0; c < 4; c++) {
                        const int kl = k4 + c;
#pragma unroll
                        for (int i2 = 0; i2 < 4; i2++)
                            if (kl > tq * 4 + i2) {
#pragma unroll
                                for (int jj = 0; jj < 4; jj++) O2d[i2][jj] += vv[c][jj];
                            }
                    }
                }
            }
        } else {
            // fully-masked future chunk: accumulate column sums of V (suffix term)
            for (int k4 = 0; k4 < 64; k4 += 4) {
#pragma unroll
                for (int jj = 0; jj < 4; jj++) {
                    us4_t vr = *(const us4_t*)&Vt[(tk + 16 * jj) * KS_STR + k4];
#pragma unroll
                    for (int c = 0; c < 4; c++) csacc[jj] += b2f(vr[c]);
                }
            }
        }
    }

    // out[q][d] = O/l - 1e9 * (suffix-sum of V)
#pragma unroll
    for (int i2 = 0; i2 < 4; i2++) {
        const float inv_l = 1.f / l_run[i2];
        const size_t rowbase = ((size_t)(b * S_ + q0 + tq * 4 + i2)) * D_ + h * HD_;
#pragma unroll
        for (int jj = 0; jj < 4; jj++) {
            const float val = O[i2][jj] * inv_l - 1e9f * (csacc[jj] + O2d[i2][jj]);
            Out[rowbase + tk + 16 * jj] = f2b(val);
        }
    }
}

// ---------------- launch ----------------
extern "C" void kernel_launch(void* const* d_in, const int* in_sizes, int n_in,
                              void* d_out, int out_size, void* d_ws, size_t ws_size,
                              hipStream_t stream) {
    const float* x     = (const float*)d_in[0];
    const float* Wq    = (const float*)d_in[1];  const float* bq = (const float*)d_in[2];
    const float* Wk    = (const float*)d_in[3];  const float* bk = (const float*)d_in[4];
    const float* Wv    = (const float*)d_in[5];  const float* bv = (const float*)d_in[6];
    const float* Wo    = (const float*)d_in[7];  const float* bo = (const float*)d_in[8];
    const float* W1    = (const float*)d_in[9];  const float* b1 = (const float*)d_in[10];
    const float* W2    = (const float*)d_in[11]; const float* b2 = (const float*)d_in[12];
    const float* gpre  = (const float*)d_in[13]; const float* bepre  = (const float*)d_in[14];
    const float* gpost = (const float*)d_in[15]; const float* bepost = (const float*)d_in[16];

    char* ws = (char*)d_ws;
    const size_t MB = 1024 * 1024;
    unsigned short* WqT = (unsigned short*)(ws + 0 * MB);
    unsigned short* WkT = (unsigned short*)(ws + 2 * MB);
    unsigned short* WvT = (unsigned short*)(ws + 4 * MB);
    unsigned short* WoT = (unsigned short*)(ws + 6 * MB);
    unsigned short* W1T = (unsigned short*)(ws + 8 * MB);
    unsigned short* W2T = (unsigned short*)(ws + 16 * MB);
    unsigned short* xn  = (unsigned short*)(ws + 24 * MB);
    unsigned short* Qb  = (unsigned short*)(ws + 32 * MB);
    unsigned short* Kb  = (unsigned short*)(ws + 40 * MB);
    unsigned short* Vb  = (unsigned short*)(ws + 48 * MB);
    unsigned short* att = (unsigned short*)(ws + 56 * MB);
    float*          x2  = (float*)(ws + 64 * MB);
    unsigned short* x2n = (unsigned short*)(ws + 80 * MB);
    unsigned short* h1  = (unsigned short*)(ws + 24 * MB);  // reuse xn/Q/K/V region

    // weight transpose + bf16 convert
    k_transpose<<<dim3(32, 32),  256, 0, stream>>>(Wq, WqT, D_, D_);
    k_transpose<<<dim3(32, 32),  256, 0, stream>>>(Wk, WkT, D_, D_);
    k_transpose<<<dim3(32, 32),  256, 0, stream>>>(Wv, WvT, D_, D_);
    k_transpose<<<dim3(32, 32),  256, 0, stream>>>(Wo, WoT, D_, D_);
    k_transpose<<<dim3(128, 32), 256, 0, stream>>>(W1, W1T, D_, DFF_);
    k_transpose<<<dim3(32, 128), 256, 0, stream>>>(W2, W2T, DFF_, D_);

    k_layernorm<<<M_, 256, 0, stream>>>(x, gpre, bepre, xn);

    k_gemm_bt<0, 1, 0><<<dim3(8, 32), 256, 0, stream>>>(xn, WqT, bq, nullptr, Qb, M_, D_, D_);
    k_gemm_bt<0, 1, 0><<<dim3(8, 32), 256, 0, stream>>>(xn, WkT, bk, nullptr, Kb, M_, D_, D_);
    k_gemm_bt<0, 1, 0><<<dim3(8, 32), 256, 0, stream>>>(xn, WvT, bv, nullptr, Vb, M_, D_, D_);

    k_rope<<<8192, 256, 0, stream>>>(Qb, Kb);

    k_attn<<<dim3(32, 32), 256, 0, stream>>>(Qb, Kb, Vb, att);

    k_gemm_bt<0, 0, 1><<<dim3(8, 32), 256, 0, stream>>>(att, WoT, bo, x, x2, M_, D_, D_);

    k_layernorm<<<M_, 256, 0, stream>>>(x2, gpost, bepost, x2n);

    k_gemm_bt<1, 1, 0><<<dim3(32, 32), 256, 0, stream>>>(x2n, W1T, b1, nullptr, h1, M_, DFF_, D_);
    k_gemm_bt<0, 0, 1><<<dim3(8, 32), 256, 0, stream>>>(h1, W2T, b2, x2, (float*)d_out, M_, D_, DFF_);
}

// Round 2
// 437.962 us; speedup vs baseline: 2.0374x; 2.0374x over previous
//
#include <hip/hip_runtime.h>
#include <stdint.h>

#define B_ 2
#define S_ 2048
#define D_ 1024
#define H_ 16
#define HD_ 64
#define DFF_ 4096
#define M_ 4096   // B*S

typedef float           f4_t  __attribute__((ext_vector_type(4)));
typedef unsigned int    ui4_t __attribute__((ext_vector_type(4)));
typedef unsigned int    ui2_t __attribute__((ext_vector_type(2)));
typedef unsigned short  us4_t __attribute__((ext_vector_type(4)));
typedef unsigned short  us8_t __attribute__((ext_vector_type(8)));
typedef __bf16          bf8_t __attribute__((ext_vector_type(8)));

__device__ __forceinline__ float b2f(unsigned short u) {
    union { unsigned int u; float f; } v; v.u = ((unsigned int)u) << 16; return v.f;
}
__device__ __forceinline__ unsigned short f2b(float f) {
    union { float f; unsigned int u; } v; v.f = f;
    unsigned int u = v.u + 0x7fffu + ((v.u >> 16) & 1u);
    return (unsigned short)(u >> 16);
}
__device__ __forceinline__ bf8_t us2bf8(us8_t u) {
    union { us8_t u; bf8_t b; } c; c.u = u; return c.b;
}

// ---------------- transpose fp32 [R][C] -> bf16 [C][R] ----------------
__global__ __launch_bounds__(256) void k_transpose(const float* __restrict__ in,
                                                   unsigned short* __restrict__ out,
                                                   int R, int C) {
    __shared__ float tile[32][33];
    const int bc = blockIdx.x * 32, br = blockIdx.y * 32;
    const int tx = threadIdx.x & 31, ty = threadIdx.x >> 5;
#pragma unroll
    for (int i = ty; i < 32; i += 8)
        tile[i][tx] = in[(size_t)(br + i) * C + bc + tx];
    __syncthreads();
#pragma unroll
    for (int i = ty; i < 32; i += 8)
        out[(size_t)(bc + i) * R + br + tx] = f2b(tile[tx][i]);
}

// ---------------- layernorm fp32 row(1024) -> bf16 ----------------
__global__ __launch_bounds__(256) void k_layernorm(const float* __restrict__ x,
                                                   const float* __restrict__ g,
                                                   const float* __restrict__ be,
                                                   unsigned short* __restrict__ out) {
    const int row = blockIdx.x;
    const int t = threadIdx.x;
    const float* xr = x + (size_t)row * D_;
    f4_t v = *(const f4_t*)&xr[t * 4];
    float s = v[0] + v[1] + v[2] + v[3];
#pragma unroll
    for (int o = 32; o >= 1; o >>= 1) s += __shfl_down(s, o);
    __shared__ float red[4];
    const int w = t >> 6, lane = t & 63;
    if (lane == 0) red[w] = s;
    __syncthreads();
    const float mean = (red[0] + red[1] + red[2] + red[3]) * (1.f / D_);
    f4_t d;
#pragma unroll
    for (int c = 0; c < 4; c++) d[c] = v[c] - mean;
    float ss = d[0]*d[0] + d[1]*d[1] + d[2]*d[2] + d[3]*d[3];
#pragma unroll
    for (int o = 32; o >= 1; o >>= 1) ss += __shfl_down(ss, o);
    __syncthreads();
    if (lane == 0) red[w] = ss;
    __syncthreads();
    const float var = (red[0] + red[1] + red[2] + red[3]) * (1.f / D_);
    const float rstd = rsqrtf(var + 1e-5f);
    f4_t gv = *(const f4_t*)&g[t * 4];
    f4_t bv = *(const f4_t*)&be[t * 4];
    us4_t o4;
#pragma unroll
    for (int c = 0; c < 4; c++) o4[c] = f2b(d[c] * rstd * gv[c] + bv[c]);
    *(us4_t*)&out[(size_t)row * D_ + t * 4] = o4;
}

// ---------------- bf16 MFMA GEMM: C[m][n] = sum_k A[m][k]*Bt[n][k] + bias ----------------
template<int RELU, int BF16OUT, int RESID>
__global__ __launch_bounds__(256) void k_gemm_bt(const unsigned short* __restrict__ A,
                                                 const unsigned short* __restrict__ Bt,
                                                 const float* __restrict__ bias,
                                                 const float* __restrict__ resid,
                                                 void* __restrict__ Cout,
                                                 int M, int N, int K) {
    __shared__ unsigned short As[128 * 32];
    __shared__ unsigned short Bs[128 * 32];
    const int tid = threadIdx.x;
    const int m0 = blockIdx.y * 128, n0 = blockIdx.x * 128;
    const int w = tid >> 6, lane = tid & 63;
    const int wr = w >> 1, wc = w & 1;
    const int lr = lane & 15, lg = lane >> 4;

    f4_t acc[4][4] = {};

    const int r1 = tid >> 2, q1 = tid & 3;
    const unsigned short* pA1 = A + (size_t)(m0 + r1) * K + q1 * 8;
    const unsigned short* pA2 = pA1 + (size_t)64 * K;
    const unsigned short* pB1 = Bt + (size_t)(n0 + r1) * K + q1 * 8;
    const unsigned short* pB2 = pB1 + (size_t)64 * K;
    const int la1 = r1 * 32 + q1 * 8, la2 = (r1 + 64) * 32 + q1 * 8;

    for (int k0 = 0; k0 < K; k0 += 32) {
        ui4_t a1 = *(const ui4_t*)(pA1 + k0);
        ui4_t a2 = *(const ui4_t*)(pA2 + k0);
        ui4_t b1 = *(const ui4_t*)(pB1 + k0);
        ui4_t b2 = *(const ui4_t*)(pB2 + k0);
        __syncthreads();
        *(ui4_t*)&As[la1] = a1;
        *(ui4_t*)&As[la2] = a2;
        *(ui4_t*)&Bs[la1] = b1;
        *(ui4_t*)&Bs[la2] = b2;
        __syncthreads();
        bf8_t af[4], bfr[4];
#pragma unroll
        for (int f = 0; f < 4; f++) {
            af[f]  = *(const bf8_t*)&As[(wr * 64 + f * 16 + lr) * 32 + lg * 8];
            bfr[f] = *(const bf8_t*)&Bs[(wc * 64 + f * 16 + lr) * 32 + lg * 8];
        }
#pragma unroll
        for (int mf = 0; mf < 4; mf++)
#pragma unroll
            for (int nf = 0; nf < 4; nf++)
                acc[mf][nf] = __builtin_amdgcn_mfma_f32_16x16x32_bf16(af[mf], bfr[nf], acc[mf][nf], 0, 0, 0);
    }

#pragma unroll
    for (int mf = 0; mf < 4; mf++) {
#pragma unroll
        for (int nf = 0; nf < 4; nf++) {
            const int n = n0 + wc * 64 + nf * 16 + lr;
            const float bv = bias[n];
#pragma unroll
            for (int j = 0; j < 4; j++) {
                const int m = m0 + wr * 64 + mf * 16 + lg * 4 + j;
                float val = acc[mf][nf][j] + bv;
                if (RESID) val += resid[(size_t)m * N + n];
                if (RELU) val = fmaxf(val, 0.f);
                if (BF16OUT) ((unsigned short*)Cout)[(size_t)m * N + n] = f2b(val);
                else         ((float*)Cout)[(size_t)m * N + n] = val;
            }
        }
    }
}

// ---------------- RoPE in-place on bf16 Q,K [B,S,H,64] ----------------
__global__ __launch_bounds__(256) void k_rope(unsigned short* __restrict__ Q,
                                              unsigned short* __restrict__ Kt) {
    const int idx = blockIdx.x * 256 + threadIdx.x;
    const int i = idx & 31;
    const int h = (idx >> 5) & 15;
    const int s = (idx >> 9) & 2047;
    const int b = idx >> 20;
    const float freq = exp2f(-(float)i * 0.4152410118609203f);
    const float ang = (float)s * freq;
    float sn, cs;
    sincosf(ang, &sn, &cs);
    const size_t base = ((size_t)(b * S_ + s)) * D_ + h * HD_ + i;
    {
        float a = b2f(Q[base]), c2 = b2f(Q[base + 32]);
        Q[base]      = f2b(a * cs - c2 * sn);
        Q[base + 32] = f2b(c2 * cs + a * sn);
    }
    {
        float a = b2f(Kt[base]), c2 = b2f(Kt[base + 32]);
        Kt[base]      = f2b(a * cs - c2 * sn);
        Kt[base + 32] = f2b(c2 * cs + a * sn);
    }
}

// ---------------- MFMA flash attention: full-row softmax, causal PV, -1e9 suffix-V ----------------
// 4 waves/block; wave wq owns q rows [q0+wq*16, +16). Swapped operands keep
// softmax stats and O lane-local at q = lane&15.
#define ATT_STR 72   // LDS row stride (shorts): 64 + 8 pad -> 2-way conflicts max

__global__ __launch_bounds__(256) void k_attn_mfma(const unsigned short* __restrict__ Q,
                                                   const unsigned short* __restrict__ K,
                                                   const unsigned short* __restrict__ V,
                                                   unsigned short* __restrict__ Out) {
    __shared__ __align__(16) unsigned short Ks[64 * ATT_STR];      // [k][d]
    __shared__ __align__(16) unsigned short Vt[64 * ATT_STR];      // [d][k]
    __shared__ __align__(16) unsigned short Ps[4][16 * ATT_STR];   // per-wave [q][k]

    const int id = blockIdx.x;
    const int wg = (id & 7) * 128 + (id >> 3);   // XCD-chunked bijective swizzle (1024%8==0)
    const int qblk = wg & 31;
    const int bh = wg >> 5;
    const int b = bh >> 4, h = bh & 15;
    const int q0 = qblk * 64;
    const int tid = threadIdx.x;
    const int wq = tid >> 6;
    const int lane = tid & 63;
    const int lr = lane & 15, lg = lane >> 4;
    unsigned short* Pw = Ps[wq];

    // Q fragments (B-operand: row q = lr, k-dim = d), pre-scaled by 1/sqrt(64)
    bf8_t qfrag[2];
    {
        const size_t qbase = ((size_t)(b * S_ + q0 + wq * 16 + lr)) * D_ + h * HD_;
#pragma unroll
        for (int ks = 0; ks < 2; ks++) {
            us8_t raw = *(const us8_t*)(Q + qbase + ks * 32 + lg * 8);
            us8_t sc;
#pragma unroll
            for (int e = 0; e < 8; e++) sc[e] = f2b(b2f(raw[e]) * 0.125f);
            qfrag[ks] = us2bf8(sc);
        }
    }
    bf8_t ones;
    {
        us8_t o;
#pragma unroll
        for (int e = 0; e < 8; e++) o[e] = 0x3f80;
        ones = us2bf8(o);
    }

    // staging: thread loads 16B from rows row0 and row0+32, col-group g
    const int row0 = tid >> 3, g = tid & 7;
    const int row1 = row0 + 32;
    const unsigned short* pK0 = K + ((size_t)(b * S_ + row0)) * D_ + h * HD_ + g * 8;
    const unsigned short* pK1 = K + ((size_t)(b * S_ + row1)) * D_ + h * HD_ + g * 8;
    const unsigned short* pV0 = V + ((size_t)(b * S_ + row0)) * D_ + h * HD_ + g * 8;
    const unsigned short* pV1 = V + ((size_t)(b * S_ + row1)) * D_ + h * HD_ + g * 8;

    float m_run = -1e30f, l_run = 0.f;
    f4_t acc_o[4] = {};    // O^T: d = dd*16+lg*4+j, q = lr
    f4_t acc_sfx[4] = {};  // suffix-V term, same layout

    for (int kc = 0; kc < 32; kc++) {
        const size_t koff = (size_t)kc * 64 * D_;
        const ui4_t k0r = *(const ui4_t*)(pK0 + koff);
        const ui4_t k1r = *(const ui4_t*)(pK1 + koff);
        const ui4_t v0r = *(const ui4_t*)(pV0 + koff);
        const ui4_t v1r = *(const ui4_t*)(pV1 + koff);
        __syncthreads();
        *(ui4_t*)&Ks[row0 * ATT_STR + g * 8] = k0r;
        *(ui4_t*)&Ks[row1 * ATT_STR + g * 8] = k1r;
        {
            const unsigned short* v0 = (const unsigned short*)&v0r;
            const unsigned short* v1 = (const unsigned short*)&v1r;
#pragma unroll
            for (int e = 0; e < 8; e++) {
                Vt[(g * 8 + e) * ATT_STR + row0] = v0[e];
                Vt[(g * 8 + e) * ATT_STR + row1] = v1[e];
            }
        }
        __syncthreads();

        // S^T = K·Q^T : s4[kk] holds k = kk*16+lg*4+j (row), q = lr (col)
        f4_t s4[4] = {};
#pragma unroll
        for (int ks = 0; ks < 2; ks++) {
#pragma unroll
            for (int kk = 0; kk < 4; kk++) {
                bf8_t kf = *(const bf8_t*)&Ks[(kk * 16 + lr) * ATT_STR + ks * 32 + lg * 8];
                s4[kk] = __builtin_amdgcn_mfma_f32_16x16x32_bf16(kf, qfrag[ks], s4[kk], 0, 0, 0);
            }
        }

        // online softmax stats over FULL row (reference masks after softmax)
        float mx = s4[0][0];
#pragma unroll
        for (int kk = 0; kk < 4; kk++)
#pragma unroll
            for (int j = 0; j < 4; j++) mx = fmaxf(mx, s4[kk][j]);
        mx = fmaxf(mx, __shfl_xor(mx, 16));
        mx = fmaxf(mx, __shfl_xor(mx, 32));
        const float mnew = fmaxf(m_run, mx);
        const float scl = __expf(m_run - mnew);
        m_run = mnew;
        float cs = 0.f;
#pragma unroll
        for (int kk = 0; kk < 4; kk++)
#pragma unroll
            for (int j = 0; j < 4; j++) {
                const float p = __expf(s4[kk][j] - mnew);
                s4[kk][j] = p;
                cs += p;
            }
        cs += __shfl_xor(cs, 16);
        cs += __shfl_xor(cs, 32);
        l_run = l_run * scl + cs;
#pragma unroll
        for (int dd = 0; dd < 4; dd++)
#pragma unroll
            for (int j = 0; j < 4; j++) acc_o[dd][j] *= scl;

        if (kc <= qblk) {
            // write P (bf16) to per-wave LDS, masked on the diagonal chunk
            const int qb = wq * 16 + lr;
#pragma unroll
            for (int kk = 0; kk < 4; kk++) {
                const int kb = kk * 16 + lg * 4;
                ui2_t w;
                if (kc == qblk) {
                    w[0] = (kb + 0 <= qb ? (unsigned)f2b(s4[kk][0]) : 0u) |
                           ((kb + 1 <= qb ? (unsigned)f2b(s4[kk][1]) : 0u) << 16);
                    w[1] = (kb + 2 <= qb ? (unsigned)f2b(s4[kk][2]) : 0u) |
                           ((kb + 3 <= qb ? (unsigned)f2b(s4[kk][3]) : 0u) << 16);
                } else {
                    w[0] = (unsigned)f2b(s4[kk][0]) | ((unsigned)f2b(s4[kk][1]) << 16);
                    w[1] = (unsigned)f2b(s4[kk][2]) | ((unsigned)f2b(s4[kk][3]) << 16);
                }
                *(ui2_t*)&Pw[lr * ATT_STR + kk * 16 + lg * 4] = w;
            }
            // O^T += V^T · P^T  (in-wave LDS write->read, no barrier needed)
#pragma unroll
            for (int ks = 0; ks < 2; ks++) {
                bf8_t pf = *(const bf8_t*)&Pw[lr * ATT_STR + ks * 32 + lg * 8];
#pragma unroll
                for (int dd = 0; dd < 4; dd++) {
                    bf8_t vf = *(const bf8_t*)&Vt[(dd * 16 + lr) * ATT_STR + ks * 32 + lg * 8];
                    acc_o[dd] = __builtin_amdgcn_mfma_f32_16x16x32_bf16(vf, pf, acc_o[dd], 0, 0, 0);
                }
            }
            if (kc == qblk) {
                // diagonal suffix: P2[q][k] = (k > q)
#pragma unroll
                for (int kk = 0; kk < 4; kk++) {
                    const int kb = kk * 16 + lg * 4;
                    ui2_t w;
                    w[0] = (kb + 0 > qb ? 0x3f80u : 0u) | ((kb + 1 > qb ? 0x3f80u : 0u) << 16);
                    w[1] = (kb + 2 > qb ? 0x3f80u : 0u) | ((kb + 3 > qb ? 0x3f80u : 0u) << 16);
                    *(ui2_t*)&Pw[lr * ATT_STR + kk * 16 + lg * 4] = w;
                }
#pragma unroll
                for (int ks = 0; ks < 2; ks++) {
                    bf8_t pf = *(const bf8_t*)&Pw[lr * ATT_STR + ks * 32 + lg * 8];
#pragma unroll
                    for (int dd = 0; dd < 4; dd++) {
                        bf8_t vf = *(const bf8_t*)&Vt[(dd * 16 + lr) * ATT_STR + ks * 32 + lg * 8];
                        acc_sfx[dd] = __builtin_amdgcn_mfma_f32_16x16x32_bf16(vf, pf, acc_sfx[dd], 0, 0, 0);
                    }
                }
            }
        } else {
            // fully-masked future chunk: column sums of V via ones-operand MFMA
#pragma unroll
            for (int ks = 0; ks < 2; ks++) {
#pragma unroll
                for (int dd = 0; dd < 4; dd++) {
                    bf8_t vf = *(const bf8_t*)&Vt[(dd * 16 + lr) * ATT_STR + ks * 32 + lg * 8];
                    acc_sfx[dd] = __builtin_amdgcn_mfma_f32_16x16x32_bf16(vf, ones, acc_sfx[dd], 0, 0, 0);
                }
            }
        }
    }

    const float inv_l = 1.f / l_run;
    const size_t obase = ((size_t)(b * S_ + q0 + wq * 16 + lr)) * D_ + h * HD_;
#pragma unroll
    for (int dd = 0; dd < 4; dd++) {
        const float v0 = acc_o[dd][0] * inv_l - 1e9f * acc_sfx[dd][0];
        const float v1 = acc_o[dd][1] * inv_l - 1e9f * acc_sfx[dd][1];
        const float v2 = acc_o[dd][2] * inv_l - 1e9f * acc_sfx[dd][2];
        const float v3 = acc_o[dd][3] * inv_l - 1e9f * acc_sfx[dd][3];
        ui2_t w;
        w[0] = (unsigned)f2b(v0) | ((unsigned)f2b(v1) << 16);
        w[1] = (unsigned)f2b(v2) | ((unsigned)f2b(v3) << 16);
        *(ui2_t*)&Out[obase + dd * 16 + lg * 4] = w;
    }
}

// ---------------- launch ----------------
extern "C" void kernel_launch(void* const* d_in, const int* in_sizes, int n_in,
                              void* d_out, int out_size, void* d_ws, size_t ws_size,
                              hipStream_t stream) {
    const float* x     = (const float*)d_in[0];
    const float* Wq    = (const float*)d_in[1];  const float* bq = (const float*)d_in[2];
    const float* Wk    = (const float*)d_in[3];  const float* bk = (const float*)d_in[4];
    const float* Wv    = (const float*)d_in[5];  const float* bv = (const float*)d_in[6];
    const float* Wo    = (const float*)d_in[7];  const float* bo = (const float*)d_in[8];
    const float* W1    = (const float*)d_in[9];  const float* b1 = (const float*)d_in[10];
    const float* W2    = (const float*)d_in[11]; const float* b2 = (const float*)d_in[12];
    const float* gpre  = (const float*)d_in[13]; const float* bepre  = (const float*)d_in[14];
    const float* gpost = (const float*)d_in[15]; const float* bepost = (const float*)d_in[16];

    char* ws = (char*)d_ws;
    const size_t MB = 1024 * 1024;
    unsigned short* WqT = (unsigned short*)(ws + 0 * MB);
    unsigned short* WkT = (unsigned short*)(ws + 2 * MB);
    unsigned short* WvT = (unsigned short*)(ws + 4 * MB);
    unsigned short* WoT = (unsigned short*)(ws + 6 * MB);
    unsigned short* W1T = (unsigned short*)(ws + 8 * MB);
    unsigned short* W2T = (unsigned short*)(ws + 16 * MB);
    unsigned short* xn  = (unsigned short*)(ws + 24 * MB);
    unsigned short* Qb  = (unsigned short*)(ws + 32 * MB);
    unsigned short* Kb  = (unsigned short*)(ws + 40 * MB);
    unsigned short* Vb  = (unsigned short*)(ws + 48 * MB);
    unsigned short* att = (unsigned short*)(ws + 56 * MB);
    float*          x2  = (float*)(ws + 64 * MB);
    unsigned short* x2n = (unsigned short*)(ws + 80 * MB);
    unsigned short* h1  = (unsigned short*)(ws + 24 * MB);  // reuse xn/Q/K/V region

    k_transpose<<<dim3(32, 32),  256, 0, stream>>>(Wq, WqT, D_, D_);
    k_transpose<<<dim3(32, 32),  256, 0, stream>>>(Wk, WkT, D_, D_);
    k_transpose<<<dim3(32, 32),  256, 0, stream>>>(Wv, WvT, D_, D_);
    k_transpose<<<dim3(32, 32),  256, 0, stream>>>(Wo, WoT, D_, D_);
    k_transpose<<<dim3(128, 32), 256, 0, stream>>>(W1, W1T, D_, DFF_);
    k_transpose<<<dim3(32, 128), 256, 0, stream>>>(W2, W2T, DFF_, D_);

    k_layernorm<<<M_, 256, 0, stream>>>(x, gpre, bepre, xn);

    k_gemm_bt<0, 1, 0><<<dim3(8, 32), 256, 0, stream>>>(xn, WqT, bq, nullptr, Qb, M_, D_, D_);
    k_gemm_bt<0, 1, 0><<<dim3(8, 32), 256, 0, stream>>>(xn, WkT, bk, nullptr, Kb, M_, D_, D_);
    k_gemm_bt<0, 1, 0><<<dim3(8, 32), 256, 0, stream>>>(xn, WvT, bv, nullptr, Vb, M_, D_, D_);

    k_rope<<<8192, 256, 0, stream>>>(Qb, Kb);

    k_attn_mfma<<<1024, 256, 0, stream>>>(Qb, Kb, Vb, att);

    k_gemm_bt<0, 0, 1><<<dim3(8, 32), 256, 0, stream>>>(att, WoT, bo, x, x2, M_, D_, D_);

    k_layernorm<<<M_, 256, 0, stream>>>(x2, gpost, bepost, x2n);

    k_gemm_bt<1, 1, 0><<<dim3(32, 32), 256, 0, stream>>>(x2n, W1T, b1, nullptr, h1, M_, DFF_, D_);
    k_gemm_bt<0, 0, 1><<<dim3(8, 32), 256, 0, stream>>>(h1, W2T, b2, x2, (float*)d_out, M_, D_, DFF_);
}

// Round 3
// 381.839 us; speedup vs baseline: 2.3369x; 1.1470x over previous
//
#include <hip/hip_runtime.h>
#include <stdint.h>

#define B_ 2
#define S_ 2048
#define D_ 1024
#define H_ 16
#define HD_ 64
#define DFF_ 4096
#define M_ 4096        // B*S
#define QKV_STR 3072   // fused QKV row stride

typedef float           f4_t  __attribute__((ext_vector_type(4)));
typedef unsigned int    ui4_t __attribute__((ext_vector_type(4)));
typedef unsigned int    ui2_t __attribute__((ext_vector_type(2)));
typedef unsigned short  us4_t __attribute__((ext_vector_type(4)));
typedef unsigned short  us8_t __attribute__((ext_vector_type(8)));
typedef __bf16          bf8_t __attribute__((ext_vector_type(8)));

__device__ __forceinline__ float b2f(unsigned short u) {
    union { unsigned int u; float f; } v; v.u = ((unsigned int)u) << 16; return v.f;
}
__device__ __forceinline__ unsigned short f2b(float f) {
    union { float f; unsigned int u; } v; v.f = f;
    unsigned int u = v.u + 0x7fffu + ((v.u >> 16) & 1u);
    return (unsigned short)(u >> 16);
}
__device__ __forceinline__ bf8_t us2bf8(us8_t u) {
    union { us8_t u; bf8_t b; } c; c.u = u; return c.b;
}
// async global->LDS 16B per lane; lds ptr must be wave-uniform (HW adds lane*16)
__device__ __forceinline__ void gll16(const unsigned short* g, unsigned short* l) {
    __builtin_amdgcn_global_load_lds((const __attribute__((address_space(1))) unsigned int*)g,
                                     (__attribute__((address_space(3))) unsigned int*)l,
                                     16, 0, 0);
}

// ---------------- transpose fp32 [R][C] -> bf16 [C][R] ----------------
__global__ __launch_bounds__(256) void k_transpose(const float* __restrict__ in,
                                                   unsigned short* __restrict__ out,
                                                   int R, int C) {
    __shared__ float tile[32][33];
    const int bc = blockIdx.x * 32, br = blockIdx.y * 32;
    const int tx = threadIdx.x & 31, ty = threadIdx.x >> 5;
#pragma unroll
    for (int i = ty; i < 32; i += 8)
        tile[i][tx] = in[(size_t)(br + i) * C + bc + tx];
    __syncthreads();
#pragma unroll
    for (int i = ty; i < 32; i += 8)
        out[(size_t)(bc + i) * R + br + tx] = f2b(tile[tx][i]);
}

// ---------------- bias concat (bq|bk|bv) ----------------
__global__ __launch_bounds__(256) void k_bias3(const float* __restrict__ a,
                                               const float* __restrict__ b,
                                               const float* __restrict__ c,
                                               float* __restrict__ o) {
    const int t = blockIdx.x * 256 + threadIdx.x;
    if (t < 1024) o[t] = a[t];
    else if (t < 2048) o[t] = b[t - 1024];
    else o[t] = c[t - 2048];
}

// ---------------- layernorm fp32 row(1024) -> bf16 ----------------
__global__ __launch_bounds__(256) void k_layernorm(const float* __restrict__ x,
                                                   const float* __restrict__ g,
                                                   const float* __restrict__ be,
                                                   unsigned short* __restrict__ out) {
    const int row = blockIdx.x;
    const int t = threadIdx.x;
    const float* xr = x + (size_t)row * D_;
    f4_t v = *(const f4_t*)&xr[t * 4];
    float s = v[0] + v[1] + v[2] + v[3];
#pragma unroll
    for (int o = 32; o >= 1; o >>= 1) s += __shfl_down(s, o);
    __shared__ float red[4];
    const int w = t >> 6, lane = t & 63;
    if (lane == 0) red[w] = s;
    __syncthreads();
    const float mean = (red[0] + red[1] + red[2] + red[3]) * (1.f / D_);
    f4_t d;
#pragma unroll
    for (int c = 0; c < 4; c++) d[c] = v[c] - mean;
    float ss = d[0]*d[0] + d[1]*d[1] + d[2]*d[2] + d[3]*d[3];
#pragma unroll
    for (int o = 32; o >= 1; o >>= 1) ss += __shfl_down(ss, o);
    __syncthreads();
    if (lane == 0) red[w] = ss;
    __syncthreads();
    const float var = (red[0] + red[1] + red[2] + red[3]) * (1.f / D_);
    const float rstd = rsqrtf(var + 1e-5f);
    f4_t gv = *(const f4_t*)&g[t * 4];
    f4_t bv = *(const f4_t*)&be[t * 4];
    us4_t o4;
#pragma unroll
    for (int c = 0; c < 4; c++) o4[c] = f2b(d[c] * rstd * gv[c] + bv[c]);
    *(us4_t*)&out[(size_t)row * D_ + t * 4] = o4;
}

// ---------------- bf16 MFMA GEMM: C[m][n] = sum_k A[m][k]*Bt[n][k] + bias ----------------
// 128x128 tile, BK=32, 4 waves (2x2); staging via global_load_lds width=16.
template<int RELU, int BF16OUT, int RESID>
__global__ __launch_bounds__(256) void k_gemm_bt(const unsigned short* __restrict__ A,
                                                 const unsigned short* __restrict__ Bt,
                                                 const float* __restrict__ bias,
                                                 const float* __restrict__ resid,
                                                 void* __restrict__ Cout,
                                                 int M, int N, int K) {
    __shared__ __align__(16) unsigned short As[128 * 32];
    __shared__ __align__(16) unsigned short Bs[128 * 32];
    const int tid = threadIdx.x;
    const int m0 = blockIdx.y * 128, n0 = blockIdx.x * 128;
    const int w = tid >> 6, lane = tid & 63;
    const int wr = w >> 1, wc = w & 1;
    const int lr = lane & 15, lg = lane >> 4;

    f4_t acc[4][4] = {};

    // staging map: LDS 16B-chunk index == tid (first half) / tid+256 (second half)
    const int r1 = tid >> 2, q1 = tid & 3;
    const unsigned short* pA1 = A + (size_t)(m0 + r1) * K + q1 * 8;
    const unsigned short* pA2 = pA1 + (size_t)64 * K;
    const unsigned short* pB1 = Bt + (size_t)(n0 + r1) * K + q1 * 8;
    const unsigned short* pB2 = pB1 + (size_t)64 * K;
    unsigned short* ldsA1 = As + (size_t)(w * 512);          // wave-uniform, bytes w*1024
    unsigned short* ldsA2 = As + (size_t)(2048 + w * 512);
    unsigned short* ldsB1 = Bs + (size_t)(w * 512);
    unsigned short* ldsB2 = Bs + (size_t)(2048 + w * 512);

    for (int k0 = 0; k0 < K; k0 += 32) {
        __syncthreads();               // previous tile consumed
        gll16(pA1 + k0, ldsA1);
        gll16(pA2 + k0, ldsA2);
        gll16(pB1 + k0, ldsB1);
        gll16(pB2 + k0, ldsB2);
        __syncthreads();               // compiler drains vmcnt before barrier
        bf8_t af[4], bfr[4];
#pragma unroll
        for (int f = 0; f < 4; f++) {
            af[f]  = *(const bf8_t*)&As[(wr * 64 + f * 16 + lr) * 32 + lg * 8];
            bfr[f] = *(const bf8_t*)&Bs[(wc * 64 + f * 16 + lr) * 32 + lg * 8];
        }
#pragma unroll
        for (int mf = 0; mf < 4; mf++)
#pragma unroll
            for (int nf = 0; nf < 4; nf++)
                acc[mf][nf] = __builtin_amdgcn_mfma_f32_16x16x32_bf16(af[mf], bfr[nf], acc[mf][nf], 0, 0, 0);
    }

#pragma unroll
    for (int mf = 0; mf < 4; mf++) {
#pragma unroll
        for (int nf = 0; nf < 4; nf++) {
            const int n = n0 + wc * 64 + nf * 16 + lr;
            const float bv = bias[n];
#pragma unroll
            for (int j = 0; j < 4; j++) {
                const int m = m0 + wr * 64 + mf * 16 + lg * 4 + j;
                float val = acc[mf][nf][j] + bv;
                if (RESID) val += resid[(size_t)m * N + n];
                if (RELU) val = fmaxf(val, 0.f);
                if (BF16OUT) ((unsigned short*)Cout)[(size_t)m * N + n] = f2b(val);
                else         ((float*)Cout)[(size_t)m * N + n] = val;
            }
        }
    }
}

// ---------------- RoPE in-place on fused QKV (Q at col 0, K at col 1024) ----------------
__global__ __launch_bounds__(256) void k_rope(unsigned short* __restrict__ QKV) {
    const int idx = blockIdx.x * 256 + threadIdx.x;
    const int i = idx & 31;
    const int h = (idx >> 5) & 15;
    const int s = (idx >> 9) & 2047;
    const int b = idx >> 20;
    const float freq = exp2f(-(float)i * 0.4152410118609203f);
    const float ang = (float)s * freq;
    float sn, cs;
    sincosf(ang, &sn, &cs);
    const size_t base = ((size_t)(b * S_ + s)) * QKV_STR + h * HD_ + i;
    {
        float a = b2f(QKV[base]), c2 = b2f(QKV[base + 32]);
        QKV[base]      = f2b(a * cs - c2 * sn);
        QKV[base + 32] = f2b(c2 * cs + a * sn);
    }
    {
        float a = b2f(QKV[base + 1024]), c2 = b2f(QKV[base + 1024 + 32]);
        QKV[base + 1024]      = f2b(a * cs - c2 * sn);
        QKV[base + 1024 + 32] = f2b(c2 * cs + a * sn);
    }
}

// ---------------- V column totals per (b,h): tot[bh][d] = sum_s V[s][d] ----------------
__global__ __launch_bounds__(256) void k_vtotal(const unsigned short* __restrict__ V,
                                                float* __restrict__ tot) {
    const int bh = blockIdx.x, b = bh >> 4, h = bh & 15;
    const int d = threadIdx.x & 63, part = threadIdx.x >> 6;
    const unsigned short* base = V + ((size_t)(b * S_) + part * 512) * QKV_STR + h * HD_ + d;
    float a0 = 0.f, a1 = 0.f, a2 = 0.f, a3 = 0.f;
    for (int s = 0; s < 512; s += 4) {
        a0 += b2f(base[(size_t)(s + 0) * QKV_STR]);
        a1 += b2f(base[(size_t)(s + 1) * QKV_STR]);
        a2 += b2f(base[(size_t)(s + 2) * QKV_STR]);
        a3 += b2f(base[(size_t)(s + 3) * QKV_STR]);
    }
    __shared__ float red[4][64];
    red[part][d] = a0 + a1 + a2 + a3;
    __syncthreads();
    if (part == 0) tot[bh * 64 + d] = red[0][d] + red[1][d] + red[2][d] + red[3][d];
}

// ---------------- MFMA flash attention ----------------
// full-row softmax stats; causal PV; mask-after-softmax -1e9 term via
// suffix = vtotal - prefix (prefix accumulated on staged chunks only).
#define KS_STRIDE 72   // K tile pad: 64+8

__global__ __launch_bounds__(256) void k_attn_mfma(const unsigned short* __restrict__ QKV,
                                                   const float* __restrict__ vtot,
                                                   unsigned short* __restrict__ Out) {
    __shared__ __align__(16) unsigned short Ks[64 * KS_STRIDE];    // [k][d] padded
    __shared__ __align__(16) unsigned short Vt[64 * 64];           // [d][kv] chunk-swizzled
    __shared__ __align__(16) unsigned short Ps[4][16 * KS_STRIDE]; // per-wave [q][k]

    const int id = blockIdx.x;
    const int wg = (id & 7) * 128 + (id >> 3);   // XCD-chunked bijective swizzle
    const int qblk = 31 - (wg & 31);             // heavy-first for tail balance
    const int bh = wg >> 5;
    const int b = bh >> 4, h = bh & 15;
    const int q0 = qblk * 64;
    const int tid = threadIdx.x;
    const int wq = tid >> 6;
    const int lane = tid & 63;
    const int lr = lane & 15, lg = lane >> 4;
    unsigned short* Pw = Ps[wq];

    const unsigned short* Qp = QKV;
    const unsigned short* Kp = QKV + 1024;
    const unsigned short* Vp = QKV + 2048;

    // Q fragments (B-operand: q = lr, k-dim = d), pre-scaled by 1/8
    bf8_t qfrag[2];
    {
        const size_t qbase = ((size_t)(b * S_ + q0 + wq * 16 + lr)) * QKV_STR + h * HD_;
#pragma unroll
        for (int ks = 0; ks < 2; ks++) {
            us8_t raw = *(const us8_t*)(Qp + qbase + ks * 32 + lg * 8);
            us8_t sc;
#pragma unroll
            for (int e = 0; e < 8; e++) sc[e] = f2b(b2f(raw[e]) * 0.125f);
            qfrag[ks] = us2bf8(sc);
        }
    }
    bf8_t ones;
    {
        us8_t o;
#pragma unroll
        for (int e = 0; e < 8; e++) o[e] = 0x3f80;
        ones = us2bf8(o);
    }

    // staging: thread handles rows row0 (=tid>>3) and row0+32, 16B col-group g
    const int row0 = tid >> 3, g = tid & 7;
    const int row1 = row0 + 32;
    const int r7 = row0 & 7;
    const int wv = tid >> 6;   // row0>>3 == wave id
    const unsigned short* pK0 = Kp + ((size_t)(b * S_ + row0)) * QKV_STR + h * HD_ + g * 8;
    const unsigned short* pK1 = Kp + ((size_t)(b * S_ + row1)) * QKV_STR + h * HD_ + g * 8;
    const unsigned short* pV0 = Vp + ((size_t)(b * S_ + row0)) * QKV_STR + h * HD_ + g * 8;
    const unsigned short* pV1 = Vp + ((size_t)(b * S_ + row1)) * QKV_STR + h * HD_ + g * 8;

    float m_run = -1e30f, l_run = 0.f;
    f4_t acc_o[4] = {};    // O^T: d = dd*16+lg*4+j, q = lr
    f4_t acc_pre[4] = {};  // prefix column-sums of V (k <= q), same layout

    const int qb = wq * 16 + lr;

    for (int kc = 0; kc < 32; kc++) {
        const size_t koff = (size_t)kc * 64 * QKV_STR;
        const bool needV = (kc <= qblk);
        const ui4_t k0r = *(const ui4_t*)(pK0 + koff);
        const ui4_t k1r = *(const ui4_t*)(pK1 + koff);
        ui4_t v0r = {}, v1r = {};
        if (needV) {
            v0r = *(const ui4_t*)(pV0 + koff);
            v1r = *(const ui4_t*)(pV1 + koff);
        }
        __syncthreads();
        *(ui4_t*)&Ks[row0 * KS_STRIDE + g * 8] = k0r;
        *(ui4_t*)&Ks[row1 * KS_STRIDE + g * 8] = k1r;
        if (needV) {
            const unsigned short* v0 = (const unsigned short*)&v0r;
            const unsigned short* v1 = (const unsigned short*)&v1r;
            const int sw0 = (wv ^ g) << 3;
            const int sw1 = ((wv + 4) ^ g) << 3;
#pragma unroll
            for (int e = 0; e < 8; e++) {
                const int d = g * 8 + e;
                Vt[d * 64 + sw0 + r7] = v0[e];   // chunk-swizzled: banks spread by g
                Vt[d * 64 + sw1 + r7] = v1[e];
            }
        }
        __syncthreads();

        // S^T = K·Q^T : s4[kk] holds k = kk*16+lg*4+j, q = lr
        f4_t s4[4] = {};
#pragma unroll
        for (int ks = 0; ks < 2; ks++) {
#pragma unroll
            for (int kk = 0; kk < 4; kk++) {
                bf8_t kf = *(const bf8_t*)&Ks[(kk * 16 + lr) * KS_STRIDE + ks * 32 + lg * 8];
                s4[kk] = __builtin_amdgcn_mfma_f32_16x16x32_bf16(kf, qfrag[ks], s4[kk], 0, 0, 0);
            }
        }

        // online softmax stats over FULL row
        float mx = s4[0][0];
#pragma unroll
        for (int kk = 0; kk < 4; kk++)
#pragma unroll
            for (int j = 0; j < 4; j++) mx = fmaxf(mx, s4[kk][j]);
        mx = fmaxf(mx, __shfl_xor(mx, 16));
        mx = fmaxf(mx, __shfl_xor(mx, 32));
        const float mnew = fmaxf(m_run, mx);
        const float scl = __expf(m_run - mnew);
        m_run = mnew;
        float cs = 0.f;
#pragma unroll
        for (int kk = 0; kk < 4; kk++)
#pragma unroll
            for (int j = 0; j < 4; j++) {
                const float p = __expf(s4[kk][j] - mnew);
                s4[kk][j] = p;
                cs += p;
            }
        cs += __shfl_xor(cs, 16);
        cs += __shfl_xor(cs, 32);
        l_run = l_run * scl + cs;
#pragma unroll
        for (int dd = 0; dd < 4; dd++)
#pragma unroll
            for (int j = 0; j < 4; j++) acc_o[dd][j] *= scl;

        if (needV) {
            // write P (bf16) masked on diagonal chunk
#pragma unroll
            for (int kk = 0; kk < 4; kk++) {
                const int kb = kk * 16 + lg * 4;
                ui2_t wd;
                if (kc == qblk) {
                    wd[0] = (kb + 0 <= qb ? (unsigned)f2b(s4[kk][0]) : 0u) |
                            ((kb + 1 <= qb ? (unsigned)f2b(s4[kk][1]) : 0u) << 16);
                    wd[1] = (kb + 2 <= qb ? (unsigned)f2b(s4[kk][2]) : 0u) |
                            ((kb + 3 <= qb ? (unsigned)f2b(s4[kk][3]) : 0u) << 16);
                } else {
                    wd[0] = (unsigned)f2b(s4[kk][0]) | ((unsigned)f2b(s4[kk][1]) << 16);
                    wd[1] = (unsigned)f2b(s4[kk][2]) | ((unsigned)f2b(s4[kk][3]) << 16);
                }
                *(ui2_t*)&Pw[lr * KS_STRIDE + kk * 16 + lg * 4] = wd;
            }
            // O^T += V^T · P^T  (in-wave LDS write->read)
#pragma unroll
            for (int ks = 0; ks < 2; ks++) {
                bf8_t pf = *(const bf8_t*)&Pw[lr * KS_STRIDE + ks * 32 + lg * 8];
#pragma unroll
                for (int dd = 0; dd < 4; dd++) {
                    bf8_t vf = *(const bf8_t*)&Vt[(dd * 16 + lr) * 64 +
                                                  (((ks * 4 + lg) ^ ((dd * 2 + (lr >> 3)) & 7)) << 3)];
                    acc_o[dd] = __builtin_amdgcn_mfma_f32_16x16x32_bf16(vf, pf, acc_o[dd], 0, 0, 0);
                }
            }
            if (kc < qblk) {
                // full-chunk prefix column sums
#pragma unroll
                for (int ks = 0; ks < 2; ks++) {
#pragma unroll
                    for (int dd = 0; dd < 4; dd++) {
                        bf8_t vf = *(const bf8_t*)&Vt[(dd * 16 + lr) * 64 +
                                                      (((ks * 4 + lg) ^ ((dd * 2 + (lr >> 3)) & 7)) << 3)];
                        acc_pre[dd] = __builtin_amdgcn_mfma_f32_16x16x32_bf16(vf, ones, acc_pre[dd], 0, 0, 0);
                    }
                }
            } else {
                // diagonal: prefix only over k <= q
#pragma unroll
                for (int kk = 0; kk < 4; kk++) {
                    const int kb = kk * 16 + lg * 4;
                    ui2_t wd;
                    wd[0] = (kb + 0 <= qb ? 0x3f80u : 0u) | ((kb + 1 <= qb ? 0x3f80u : 0u) << 16);
                    wd[1] = (kb + 2 <= qb ? 0x3f80u : 0u) | ((kb + 3 <= qb ? 0x3f80u : 0u) << 16);
                    *(ui2_t*)&Pw[lr * KS_STRIDE + kk * 16 + lg * 4] = wd;
                }
#pragma unroll
                for (int ks = 0; ks < 2; ks++) {
                    bf8_t pf = *(const bf8_t*)&Pw[lr * KS_STRIDE + ks * 32 + lg * 8];
#pragma unroll
                    for (int dd = 0; dd < 4; dd++) {
                        bf8_t vf = *(const bf8_t*)&Vt[(dd * 16 + lr) * 64 +
                                                      (((ks * 4 + lg) ^ ((dd * 2 + (lr >> 3)) & 7)) << 3)];
                        acc_pre[dd] = __builtin_amdgcn_mfma_f32_16x16x32_bf16(vf, pf, acc_pre[dd], 0, 0, 0);
                    }
                }
            }
        }
    }

    // out = O/l - 1e9 * (vtotal - prefix)
    const float inv_l = 1.f / l_run;
    const size_t obase = ((size_t)(b * S_ + q0 + wq * 16 + lr)) * D_ + h * HD_;
#pragma unroll
    for (int dd = 0; dd < 4; dd++) {
        const f4_t tv = *(const f4_t*)&vtot[bh * 64 + dd * 16 + lg * 4];
        ui2_t wd;
        const float v0 = acc_o[dd][0] * inv_l - 1e9f * (tv[0] - acc_pre[dd][0]);
        const float v1 = acc_o[dd][1] * inv_l - 1e9f * (tv[1] - acc_pre[dd][1]);
        const float v2 = acc_o[dd][2] * inv_l - 1e9f * (tv[2] - acc_pre[dd][2]);
        const float v3 = acc_o[dd][3] * inv_l - 1e9f * (tv[3] - acc_pre[dd][3]);
        wd[0] = (unsigned)f2b(v0) | ((unsigned)f2b(v1) << 16);
        wd[1] = (unsigned)f2b(v2) | ((unsigned)f2b(v3) << 16);
        *(ui2_t*)&Out[obase + dd * 16 + lg * 4] = wd;
    }
}

// ---------------- launch ----------------
extern "C" void kernel_launch(void* const* d_in, const int* in_sizes, int n_in,
                              void* d_out, int out_size, void* d_ws, size_t ws_size,
                              hipStream_t stream) {
    const float* x     = (const float*)d_in[0];
    const float* Wq    = (const float*)d_in[1];  const float* bq = (const float*)d_in[2];
    const float* Wk    = (const float*)d_in[3];  const float* bk = (const float*)d_in[4];
    const float* Wv    = (const float*)d_in[5];  const float* bv = (const float*)d_in[6];
    const float* Wo    = (const float*)d_in[7];  const float* bo = (const float*)d_in[8];
    const float* W1    = (const float*)d_in[9];  const float* b1 = (const float*)d_in[10];
    const float* W2    = (const float*)d_in[11]; const float* b2 = (const float*)d_in[12];
    const float* gpre  = (const float*)d_in[13]; const float* bepre  = (const float*)d_in[14];
    const float* gpost = (const float*)d_in[15]; const float* bepost = (const float*)d_in[16];

    char* ws = (char*)d_ws;
    const size_t MB = 1024 * 1024;
    unsigned short* WqkvT = (unsigned short*)(ws + 0 * MB);    // [3072][1024] bf16, 6MB
    unsigned short* WoT   = (unsigned short*)(ws + 6 * MB);    // 2MB
    unsigned short* W1T   = (unsigned short*)(ws + 8 * MB);    // 8MB
    unsigned short* W2T   = (unsigned short*)(ws + 16 * MB);   // 8MB
    unsigned short* xn    = (unsigned short*)(ws + 24 * MB);   // 8MB
    unsigned short* QKV   = (unsigned short*)(ws + 32 * MB);   // 24MB
    unsigned short* att   = (unsigned short*)(ws + 56 * MB);   // 8MB
    unsigned short* h1    = (unsigned short*)(ws + 24 * MB);   // 32MB (over xn+QKV, dead then)
    unsigned short* x2n   = (unsigned short*)(ws + 56 * MB);   // 8MB (over att, dead then)
    float*          x2    = (float*)(ws + 64 * MB);            // 16MB
    float*          bqkv  = (float*)(ws + 80 * MB);            // 12KB
    float*          vtot  = (float*)(ws + 80 * MB + 16384);    // 8KB

    // weight transpose + bf16 convert (QKV fused: rows 0..3071 = Wq|Wk|Wv)
    k_transpose<<<dim3(32, 32),  256, 0, stream>>>(Wq, WqkvT, D_, D_);
    k_transpose<<<dim3(32, 32),  256, 0, stream>>>(Wk, WqkvT + 1024 * 1024, D_, D_);
    k_transpose<<<dim3(32, 32),  256, 0, stream>>>(Wv, WqkvT + 2048 * 1024, D_, D_);
    k_transpose<<<dim3(32, 32),  256, 0, stream>>>(Wo, WoT, D_, D_);
    k_transpose<<<dim3(128, 32), 256, 0, stream>>>(W1, W1T, D_, DFF_);
    k_transpose<<<dim3(32, 128), 256, 0, stream>>>(W2, W2T, DFF_, D_);
    k_bias3<<<12, 256, 0, stream>>>(bq, bk, bv, bqkv);

    k_layernorm<<<M_, 256, 0, stream>>>(x, gpre, bepre, xn);

    // fused QKV projection: [M][3072]
    k_gemm_bt<0, 1, 0><<<dim3(24, 32), 256, 0, stream>>>(xn, WqkvT, bqkv, nullptr, QKV, M_, QKV_STR, D_);

    k_rope<<<8192, 256, 0, stream>>>(QKV);
    k_vtotal<<<32, 256, 0, stream>>>(QKV + 2048, vtot);

    k_attn_mfma<<<1024, 256, 0, stream>>>(QKV, vtot, att);

    k_gemm_bt<0, 0, 1><<<dim3(8, 32), 256, 0, stream>>>(att, WoT, bo, x, x2, M_, D_, D_);

    k_layernorm<<<M_, 256, 0, stream>>>(x2, gpost, bepost, x2n);

    k_gemm_bt<1, 1, 0><<<dim3(32, 32), 256, 0, stream>>>(x2n, W1T, b1, nullptr, h1, M_, DFF_, D_);
    k_gemm_bt<0, 0, 1><<<dim3(8, 32), 256, 0, stream>>>(h1, W2T, b2, x2, (float*)d_out, M_, D_, DFF_);
}

// Round 4
// 376.914 us; speedup vs baseline: 2.3674x; 1.0131x over previous
//
#include <hip/hip_runtime.h>
#include <stdint.h>

#define B_ 2
#define S_ 2048
#define D_ 1024
#define H_ 16
#define HD_ 64
#define DFF_ 4096
#define M_ 4096        // B*S
#define QKV_STR 3072   // fused QKV row stride

typedef float           f4_t  __attribute__((ext_vector_type(4)));
typedef unsigned int    ui4_t __attribute__((ext_vector_type(4)));
typedef unsigned int    ui2_t __attribute__((ext_vector_type(2)));
typedef unsigned short  us4_t __attribute__((ext_vector_type(4)));
typedef unsigned short  us8_t __attribute__((ext_vector_type(8)));
typedef __bf16          bf8_t __attribute__((ext_vector_type(8)));

__device__ __forceinline__ float b2f(unsigned short u) {
    union { unsigned int u; float f; } v; v.u = ((unsigned int)u) << 16; return v.f;
}
__device__ __forceinline__ unsigned short f2b(float f) {
    union { float f; unsigned int u; } v; v.f = f;
    unsigned int u = v.u + 0x7fffu + ((v.u >> 16) & 1u);
    return (unsigned short)(u >> 16);
}
// packed f32x2 -> bf16x2 in one VALU op (lo in [15:0], hi in [31:16])
__device__ __forceinline__ unsigned cvt_pk_bf16(float lo, float hi) {
    unsigned r;
    asm("v_cvt_pk_bf16_f32 %0, %1, %2" : "=v"(r) : "v"(lo), "v"(hi));
    return r;
}
__device__ __forceinline__ bf8_t us2bf8(us8_t u) {
    union { us8_t u; bf8_t b; } c; c.u = u; return c.b;
}
// async global->LDS 16B per lane; lds ptr must be wave-uniform (HW adds lane*16)
__device__ __forceinline__ void gll16(const unsigned short* g, unsigned short* l) {
    __builtin_amdgcn_global_load_lds((const __attribute__((address_space(1))) unsigned int*)g,
                                     (__attribute__((address_space(3))) unsigned int*)l,
                                     16, 0, 0);
}

// ---------------- transpose fp32 [R][C] -> bf16 [C][R] ----------------
__global__ __launch_bounds__(256) void k_transpose(const float* __restrict__ in,
                                                   unsigned short* __restrict__ out,
                                                   int R, int C) {
    __shared__ float tile[32][33];
    const int bc = blockIdx.x * 32, br = blockIdx.y * 32;
    const int tx = threadIdx.x & 31, ty = threadIdx.x >> 5;
#pragma unroll
    for (int i = ty; i < 32; i += 8)
        tile[i][tx] = in[(size_t)(br + i) * C + bc + tx];
    __syncthreads();
#pragma unroll
    for (int i = ty; i < 32; i += 8)
        out[(size_t)(bc + i) * R + br + tx] = f2b(tile[tx][i]);
}

// ---------------- bias concat (bq|bk|bv) ----------------
__global__ __launch_bounds__(256) void k_bias3(const float* __restrict__ a,
                                               const float* __restrict__ b,
                                               const float* __restrict__ c,
                                               float* __restrict__ o) {
    const int t = blockIdx.x * 256 + threadIdx.x;
    if (t < 1024) o[t] = a[t];
    else if (t < 2048) o[t] = b[t - 1024];
    else o[t] = c[t - 2048];
}

// ---------------- layernorm fp32 row(1024) -> bf16 ----------------
__global__ __launch_bounds__(256) void k_layernorm(const float* __restrict__ x,
                                                   const float* __restrict__ g,
                                                   const float* __restrict__ be,
                                                   unsigned short* __restrict__ out) {
    const int row = blockIdx.x;
    const int t = threadIdx.x;
    const float* xr = x + (size_t)row * D_;
    f4_t v = *(const f4_t*)&xr[t * 4];
    float s = v[0] + v[1] + v[2] + v[3];
#pragma unroll
    for (int o = 32; o >= 1; o >>= 1) s += __shfl_down(s, o);
    __shared__ float red[4];
    const int w = t >> 6, lane = t & 63;
    if (lane == 0) red[w] = s;
    __syncthreads();
    const float mean = (red[0] + red[1] + red[2] + red[3]) * (1.f / D_);
    f4_t d;
#pragma unroll
    for (int c = 0; c < 4; c++) d[c] = v[c] - mean;
    float ss = d[0]*d[0] + d[1]*d[1] + d[2]*d[2] + d[3]*d[3];
#pragma unroll
    for (int o = 32; o >= 1; o >>= 1) ss += __shfl_down(ss, o);
    __syncthreads();
    if (lane == 0) red[w] = ss;
    __syncthreads();
    const float var = (red[0] + red[1] + red[2] + red[3]) * (1.f / D_);
    const float rstd = rsqrtf(var + 1e-5f);
    f4_t gv = *(const f4_t*)&g[t * 4];
    f4_t bv = *(const f4_t*)&be[t * 4];
    us4_t o4;
#pragma unroll
    for (int c = 0; c < 4; c++) o4[c] = f2b(d[c] * rstd * gv[c] + bv[c]);
    *(us4_t*)&out[(size_t)row * D_ + t * 4] = o4;
}

// ---------------- bf16 MFMA GEMM 128x128, BK=32, 4 waves (2x2) ----------------
template<int RELU, int BF16OUT, int RESID>
__global__ __launch_bounds__(256) void k_gemm_bt(const unsigned short* __restrict__ A,
                                                 const unsigned short* __restrict__ Bt,
                                                 const float* __restrict__ bias,
                                                 const float* __restrict__ resid,
                                                 void* __restrict__ Cout,
                                                 int M, int N, int K) {
    __shared__ __align__(16) unsigned short As[128 * 32];
    __shared__ __align__(16) unsigned short Bs[128 * 32];
    const int tid = threadIdx.x;
    const int m0 = blockIdx.y * 128, n0 = blockIdx.x * 128;
    const int w = tid >> 6, lane = tid & 63;
    const int wr = w >> 1, wc = w & 1;
    const int lr = lane & 15, lg = lane >> 4;

    f4_t acc[4][4] = {};

    const int r1 = tid >> 2, q1 = tid & 3;
    const unsigned short* pA1 = A + (size_t)(m0 + r1) * K + q1 * 8;
    const unsigned short* pA2 = pA1 + (size_t)64 * K;
    const unsigned short* pB1 = Bt + (size_t)(n0 + r1) * K + q1 * 8;
    const unsigned short* pB2 = pB1 + (size_t)64 * K;
    unsigned short* ldsA1 = As + (size_t)(w * 512);
    unsigned short* ldsA2 = As + (size_t)(2048 + w * 512);
    unsigned short* ldsB1 = Bs + (size_t)(w * 512);
    unsigned short* ldsB2 = Bs + (size_t)(2048 + w * 512);

    for (int k0 = 0; k0 < K; k0 += 32) {
        __syncthreads();
        gll16(pA1 + k0, ldsA1);
        gll16(pA2 + k0, ldsA2);
        gll16(pB1 + k0, ldsB1);
        gll16(pB2 + k0, ldsB2);
        __syncthreads();
        bf8_t af[4], bfr[4];
#pragma unroll
        for (int f = 0; f < 4; f++) {
            af[f]  = *(const bf8_t*)&As[(wr * 64 + f * 16 + lr) * 32 + lg * 8];
            bfr[f] = *(const bf8_t*)&Bs[(wc * 64 + f * 16 + lr) * 32 + lg * 8];
        }
#pragma unroll
        for (int mf = 0; mf < 4; mf++)
#pragma unroll
            for (int nf = 0; nf < 4; nf++)
                acc[mf][nf] = __builtin_amdgcn_mfma_f32_16x16x32_bf16(af[mf], bfr[nf], acc[mf][nf], 0, 0, 0);
    }

#pragma unroll
    for (int mf = 0; mf < 4; mf++) {
#pragma unroll
        for (int nf = 0; nf < 4; nf++) {
            const int n = n0 + wc * 64 + nf * 16 + lr;
            const float bv = bias[n];
#pragma unroll
            for (int j = 0; j < 4; j++) {
                const int m = m0 + wr * 64 + mf * 16 + lg * 4 + j;
                float val = acc[mf][nf][j] + bv;
                if (RESID) val += resid[(size_t)m * N + n];
                if (RELU) val = fmaxf(val, 0.f);
                if (BF16OUT) ((unsigned short*)Cout)[(size_t)m * N + n] = f2b(val);
                else         ((float*)Cout)[(size_t)m * N + n] = val;
            }
        }
    }
}

// ---------------- bf16 MFMA GEMM 64x128 tile (2 blocks/CU at grid 512) ----------------
// 4 waves 2x2: wave = 32m x 64n; acc[2][4]. For M=4096,N=1024 grids.
template<int RELU, int BF16OUT, int RESID>
__global__ __launch_bounds__(256) void k_gemm64(const unsigned short* __restrict__ A,
                                                const unsigned short* __restrict__ Bt,
                                                const float* __restrict__ bias,
                                                const float* __restrict__ resid,
                                                void* __restrict__ Cout,
                                                int M, int N, int K) {
    __shared__ __align__(16) unsigned short As[64 * 32];
    __shared__ __align__(16) unsigned short Bs[128 * 32];
    const int tid = threadIdx.x;
    const int m0 = blockIdx.y * 64, n0 = blockIdx.x * 128;
    const int w = tid >> 6, lane = tid & 63;
    const int wr = w >> 1, wc = w & 1;
    const int lr = lane & 15, lg = lane >> 4;

    f4_t acc[2][4] = {};

    const int r1 = tid >> 2, q1 = tid & 3;
    const unsigned short* pA1 = A + (size_t)(m0 + r1) * K + q1 * 8;          // 256 chunks
    const unsigned short* pB1 = Bt + (size_t)(n0 + r1) * K + q1 * 8;         // 512 chunks
    const unsigned short* pB2 = pB1 + (size_t)64 * K;
    unsigned short* ldsA1 = As + (size_t)(w * 512);
    unsigned short* ldsB1 = Bs + (size_t)(w * 512);
    unsigned short* ldsB2 = Bs + (size_t)(2048 + w * 512);

    for (int k0 = 0; k0 < K; k0 += 32) {
        __syncthreads();
        gll16(pA1 + k0, ldsA1);
        gll16(pB1 + k0, ldsB1);
        gll16(pB2 + k0, ldsB2);
        __syncthreads();
        bf8_t af[2], bfr[4];
#pragma unroll
        for (int f = 0; f < 2; f++)
            af[f] = *(const bf8_t*)&As[(wr * 32 + f * 16 + lr) * 32 + lg * 8];
#pragma unroll
        for (int f = 0; f < 4; f++)
            bfr[f] = *(const bf8_t*)&Bs[(wc * 64 + f * 16 + lr) * 32 + lg * 8];
#pragma unroll
        for (int mf = 0; mf < 2; mf++)
#pragma unroll
            for (int nf = 0; nf < 4; nf++)
                acc[mf][nf] = __builtin_amdgcn_mfma_f32_16x16x32_bf16(af[mf], bfr[nf], acc[mf][nf], 0, 0, 0);
    }

#pragma unroll
    for (int mf = 0; mf < 2; mf++) {
#pragma unroll
        for (int nf = 0; nf < 4; nf++) {
            const int n = n0 + wc * 64 + nf * 16 + lr;
            const float bv = bias[n];
#pragma unroll
            for (int j = 0; j < 4; j++) {
                const int m = m0 + wr * 32 + mf * 16 + lg * 4 + j;
                float val = acc[mf][nf][j] + bv;
                if (RESID) val += resid[(size_t)m * N + n];
                if (RELU) val = fmaxf(val, 0.f);
                if (BF16OUT) ((unsigned short*)Cout)[(size_t)m * N + n] = f2b(val);
                else         ((float*)Cout)[(size_t)m * N + n] = val;
            }
        }
    }
}

// ---------------- RoPE in-place on fused QKV (Q at col 0, K at col 1024) ----------------
__global__ __launch_bounds__(256) void k_rope(unsigned short* __restrict__ QKV) {
    const int idx = blockIdx.x * 256 + threadIdx.x;
    const int i = idx & 31;
    const int h = (idx >> 5) & 15;
    const int s = (idx >> 9) & 2047;
    const int b = idx >> 20;
    const float freq = exp2f(-(float)i * 0.4152410118609203f);
    const float ang = (float)s * freq;
    float sn, cs;
    sincosf(ang, &sn, &cs);
    const size_t base = ((size_t)(b * S_ + s)) * QKV_STR + h * HD_ + i;
    {
        float a = b2f(QKV[base]), c2 = b2f(QKV[base + 32]);
        QKV[base]      = f2b(a * cs - c2 * sn);
        QKV[base + 32] = f2b(c2 * cs + a * sn);
    }
    {
        float a = b2f(QKV[base + 1024]), c2 = b2f(QKV[base + 1024 + 32]);
        QKV[base + 1024]      = f2b(a * cs - c2 * sn);
        QKV[base + 1024 + 32] = f2b(c2 * cs + a * sn);
    }
}

// ---------------- per-(b,h) chunk-prefix V column sums ----------------
// pre[bh][c][d] = sum over chunks < c of colsum(V chunk);  pre[bh][32][d] = total
__global__ __launch_bounds__(256) void k_vprefix(const unsigned short* __restrict__ V,
                                                 float* __restrict__ pre) {
    const int bh = blockIdx.x, b = bh >> 4, h = bh & 15;
    const int d = threadIdx.x & 63, part = threadIdx.x >> 6;
    __shared__ float red[4][64];
    float cum = 0.f;
    for (int c = 0; c < 32; c++) {
        const unsigned short* base = V + ((size_t)(b * S_ + c * 64 + part * 16)) * QKV_STR + h * HD_ + d;
        float s = 0.f;
#pragma unroll
        for (int r = 0; r < 16; r++) s += b2f(base[(size_t)r * QKV_STR]);
        red[part][d] = s;
        __syncthreads();
        if (part == 0) pre[((size_t)bh * 33 + c) * 64 + d] = cum;
        cum += red[0][d] + red[1][d] + red[2][d] + red[3][d];
        __syncthreads();
    }
    if (part == 0) pre[((size_t)bh * 33 + 32) * 64 + d] = cum;
}

// ---------------- MFMA flash attention ----------------
// full-row softmax stats; causal PV; mask-after-softmax -1e9 term via
// suffix = total - chunkprefix[qblk] - diagonal partial prefix (MFMA once).
#define KS_STRIDE 72   // K tile pad: 64+8

__global__ __launch_bounds__(256) void k_attn_mfma(const unsigned short* __restrict__ QKV,
                                                   const float* __restrict__ vpre,
                                                   unsigned short* __restrict__ Out) {
    __shared__ __align__(16) unsigned short Ks[64 * KS_STRIDE];    // [k][d] padded
    __shared__ __align__(16) unsigned short Vt[64 * 64];           // [d][kv] chunk-swizzled
    __shared__ __align__(16) unsigned short Ps[4][16 * KS_STRIDE]; // per-wave [q][k]

    const int id = blockIdx.x;
    const int wg = (id & 7) * 128 + (id >> 3);   // XCD-chunked bijective swizzle
    const int qblk = 31 - (wg & 31);             // heavy-first for tail balance
    const int bh = wg >> 5;
    const int b = bh >> 4, h = bh & 15;
    const int q0 = qblk * 64;
    const int tid = threadIdx.x;
    const int wq = tid >> 6;
    const int lane = tid & 63;
    const int lr = lane & 15, lg = lane >> 4;
    unsigned short* Pw = Ps[wq];

    const unsigned short* Qp = QKV;
    const unsigned short* Kp = QKV + 1024;
    const unsigned short* Vp = QKV + 2048;

    // Q fragments (B-operand: q = lr, k-dim = d), pre-scaled by 1/8
    bf8_t qfrag[2];
    {
        const size_t qbase = ((size_t)(b * S_ + q0 + wq * 16 + lr)) * QKV_STR + h * HD_;
#pragma unroll
        for (int ks = 0; ks < 2; ks++) {
            us8_t raw = *(const us8_t*)(Qp + qbase + ks * 32 + lg * 8);
            ui4_t p;
#pragma unroll
            for (int e = 0; e < 4; e++)
                p[e] = cvt_pk_bf16(b2f(raw[e * 2]) * 0.125f, b2f(raw[e * 2 + 1]) * 0.125f);
            union { ui4_t u; bf8_t b; } c; c.u = p;
            qfrag[ks] = c.b;
        }
    }

    // staging: thread handles rows row0 (=tid>>3) and row0+32, 16B col-group g
    const int row0 = tid >> 3, g = tid & 7;
    const int row1 = row0 + 32;
    const int r7 = row0 & 7;
    const int wv = tid >> 6;
    const unsigned short* pK0 = Kp + ((size_t)(b * S_ + row0)) * QKV_STR + h * HD_ + g * 8;
    const unsigned short* pK1 = Kp + ((size_t)(b * S_ + row1)) * QKV_STR + h * HD_ + g * 8;
    const unsigned short* pV0 = Vp + ((size_t)(b * S_ + row0)) * QKV_STR + h * HD_ + g * 8;
    const unsigned short* pV1 = Vp + ((size_t)(b * S_ + row1)) * QKV_STR + h * HD_ + g * 8;

    float m_run = -1e30f, l_run = 0.f;
    f4_t acc_o[4] = {};    // O^T: d = dd*16+lg*4+j, q = lr
    f4_t acc_pre[4] = {};  // diagonal partial prefix colsum of V, same layout

    const int qb = wq * 16 + lr;

    for (int kc = 0; kc < 32; kc++) {
        const size_t koff = (size_t)kc * 64 * QKV_STR;
        const bool needV = (kc <= qblk);
        const ui4_t k0r = *(const ui4_t*)(pK0 + koff);
        const ui4_t k1r = *(const ui4_t*)(pK1 + koff);
        ui4_t v0r = {}, v1r = {};
        if (needV) {
            v0r = *(const ui4_t*)(pV0 + koff);
            v1r = *(const ui4_t*)(pV1 + koff);
        }
        __syncthreads();
        *(ui4_t*)&Ks[row0 * KS_STRIDE + g * 8] = k0r;
        *(ui4_t*)&Ks[row1 * KS_STRIDE + g * 8] = k1r;
        if (needV) {
            const unsigned short* v0 = (const unsigned short*)&v0r;
            const unsigned short* v1 = (const unsigned short*)&v1r;
            const int sw0 = (wv ^ g) << 3;
            const int sw1 = ((wv + 4) ^ g) << 3;
#pragma unroll
            for (int e = 0; e < 8; e++) {
                const int d = g * 8 + e;
                Vt[d * 64 + sw0 + r7] = v0[e];
                Vt[d * 64 + sw1 + r7] = v1[e];
            }
        }
        __syncthreads();

        // S^T = K·Q^T : s4[kk] holds k = kk*16+lg*4+j, q = lr
        f4_t s4[4] = {};
#pragma unroll
        for (int ks = 0; ks < 2; ks++) {
#pragma unroll
            for (int kk = 0; kk < 4; kk++) {
                bf8_t kf = *(const bf8_t*)&Ks[(kk * 16 + lr) * KS_STRIDE + ks * 32 + lg * 8];
                s4[kk] = __builtin_amdgcn_mfma_f32_16x16x32_bf16(kf, qfrag[ks], s4[kk], 0, 0, 0);
            }
        }

        // online softmax stats over FULL row, defer-max (THR=8)
        float mx = s4[0][0];
#pragma unroll
        for (int kk = 0; kk < 4; kk++)
#pragma unroll
            for (int j = 0; j < 4; j++) mx = fmaxf(mx, s4[kk][j]);
        mx = fmaxf(mx, __shfl_xor(mx, 16));
        mx = fmaxf(mx, __shfl_xor(mx, 32));
        if (!__all(mx <= m_run + 8.f)) {
            const float mnew = fmaxf(m_run, mx);
            const float scl = __expf(m_run - mnew);
            m_run = mnew;
            l_run *= scl;
#pragma unroll
            for (int dd = 0; dd < 4; dd++)
#pragma unroll
                for (int j = 0; j < 4; j++) acc_o[dd][j] *= scl;
        }
        float cs = 0.f;
#pragma unroll
        for (int kk = 0; kk < 4; kk++)
#pragma unroll
            for (int j = 0; j < 4; j++) {
                const float p = __expf(s4[kk][j] - m_run);
                s4[kk][j] = p;
                cs += p;
            }
        cs += __shfl_xor(cs, 16);
        cs += __shfl_xor(cs, 32);
        l_run += cs;

        if (needV) {
            // write P (bf16) masked on diagonal chunk
#pragma unroll
            for (int kk = 0; kk < 4; kk++) {
                const int kb = kk * 16 + lg * 4;
                ui2_t wd;
                if (kc == qblk) {
                    wd[0] = cvt_pk_bf16(kb + 0 <= qb ? s4[kk][0] : 0.f,
                                        kb + 1 <= qb ? s4[kk][1] : 0.f);
                    wd[1] = cvt_pk_bf16(kb + 2 <= qb ? s4[kk][2] : 0.f,
                                        kb + 3 <= qb ? s4[kk][3] : 0.f);
                } else {
                    wd[0] = cvt_pk_bf16(s4[kk][0], s4[kk][1]);
                    wd[1] = cvt_pk_bf16(s4[kk][2], s4[kk][3]);
                }
                *(ui2_t*)&Pw[lr * KS_STRIDE + kk * 16 + lg * 4] = wd;
            }
            // O^T += V^T · P^T  (in-wave LDS write->read)
#pragma unroll
            for (int ks = 0; ks < 2; ks++) {
                bf8_t pf = *(const bf8_t*)&Pw[lr * KS_STRIDE + ks * 32 + lg * 8];
#pragma unroll
                for (int dd = 0; dd < 4; dd++) {
                    bf8_t vf = *(const bf8_t*)&Vt[(dd * 16 + lr) * 64 +
                                                  (((ks * 4 + lg) ^ ((dd * 2 + (lr >> 3)) & 7)) << 3)];
                    acc_o[dd] = __builtin_amdgcn_mfma_f32_16x16x32_bf16(vf, pf, acc_o[dd], 0, 0, 0);
                }
            }
            if (kc == qblk) {
                // diagonal partial prefix: P2[q][k] = (k <= q)
#pragma unroll
                for (int kk = 0; kk < 4; kk++) {
                    const int kb = kk * 16 + lg * 4;
                    ui2_t wd;
                    wd[0] = (kb + 0 <= qb ? 0x3f80u : 0u) | ((kb + 1 <= qb ? 0x3f80u : 0u) << 16);
                    wd[1] = (kb + 2 <= qb ? 0x3f80u : 0u) | ((kb + 3 <= qb ? 0x3f80u : 0u) << 16);
                    *(ui2_t*)&Pw[lr * KS_STRIDE + kk * 16 + lg * 4] = wd;
                }
#pragma unroll
                for (int ks = 0; ks < 2; ks++) {
                    bf8_t pf = *(const bf8_t*)&Pw[lr * KS_STRIDE + ks * 32 + lg * 8];
#pragma unroll
                    for (int dd = 0; dd < 4; dd++) {
                        bf8_t vf = *(const bf8_t*)&Vt[(dd * 16 + lr) * 64 +
                                                      (((ks * 4 + lg) ^ ((dd * 2 + (lr >> 3)) & 7)) << 3)];
                        acc_pre[dd] = __builtin_amdgcn_mfma_f32_16x16x32_bf16(vf, pf, acc_pre[dd], 0, 0, 0);
                    }
                }
            }
        }
    }

    // out = O/l - 1e9 * (total - chunkprefix[qblk] - diag_prefix)
    const float inv_l = 1.f / l_run;
    const float* Cq = vpre + ((size_t)bh * 33 + qblk) * 64;
    const float* Ct = vpre + ((size_t)bh * 33 + 32) * 64;
    const size_t obase = ((size_t)(b * S_ + q0 + wq * 16 + lr)) * D_ + h * HD_;
#pragma unroll
    for (int dd = 0; dd < 4; dd++) {
        const f4_t tq4 = *(const f4_t*)&Cq[dd * 16 + lg * 4];
        const f4_t tt4 = *(const f4_t*)&Ct[dd * 16 + lg * 4];
        float v[4];
#pragma unroll
        for (int j = 0; j < 4; j++)
            v[j] = acc_o[dd][j] * inv_l - 1e9f * (tt4[j] - tq4[j] - acc_pre[dd][j]);
        ui2_t wd;
        wd[0] = cvt_pk_bf16(v[0], v[1]);
        wd[1] = cvt_pk_bf16(v[2], v[3]);
        *(ui2_t*)&Out[obase + dd * 16 + lg * 4] = wd;
    }
}

// ---------------- launch ----------------
extern "C" void kernel_launch(void* const* d_in, const int* in_sizes, int n_in,
                              void* d_out, int out_size, void* d_ws, size_t ws_size,
                              hipStream_t stream) {
    const float* x     = (const float*)d_in[0];
    const float* Wq    = (const float*)d_in[1];  const float* bq = (const float*)d_in[2];
    const float* Wk    = (const float*)d_in[3];  const float* bk = (const float*)d_in[4];
    const float* Wv    = (const float*)d_in[5];  const float* bv = (const float*)d_in[6];
    const float* Wo    = (const float*)d_in[7];  const float* bo = (const float*)d_in[8];
    const float* W1    = (const float*)d_in[9];  const float* b1 = (const float*)d_in[10];
    const float* W2    = (const float*)d_in[11]; const float* b2 = (const float*)d_in[12];
    const float* gpre  = (const float*)d_in[13]; const float* bepre  = (const float*)d_in[14];
    const float* gpost = (const float*)d_in[15]; const float* bepost = (const float*)d_in[16];

    char* ws = (char*)d_ws;
    const size_t MB = 1024 * 1024;
    unsigned short* WqkvT = (unsigned short*)(ws + 0 * MB);    // [3072][1024] bf16, 6MB
    unsigned short* WoT   = (unsigned short*)(ws + 6 * MB);    // 2MB
    unsigned short* W1T   = (unsigned short*)(ws + 8 * MB);    // 8MB
    unsigned short* W2T   = (unsigned short*)(ws + 16 * MB);   // 8MB
    unsigned short* xn    = (unsigned short*)(ws + 24 * MB);   // 8MB
    unsigned short* QKV   = (unsigned short*)(ws + 32 * MB);   // 24MB
    unsigned short* att   = (unsigned short*)(ws + 56 * MB);   // 8MB
    unsigned short* h1    = (unsigned short*)(ws + 24 * MB);   // 32MB (over xn+QKV, dead then)
    unsigned short* x2n   = (unsigned short*)(ws + 56 * MB);   // 8MB (over att, dead then)
    float*          x2    = (float*)(ws + 64 * MB);            // 16MB
    float*          bqkv  = (float*)(ws + 80 * MB);            // 12KB
    float*          vpre  = (float*)(ws + 80 * MB + 16384);    // 270KB

    k_transpose<<<dim3(32, 32),  256, 0, stream>>>(Wq, WqkvT, D_, D_);
    k_transpose<<<dim3(32, 32),  256, 0, stream>>>(Wk, WqkvT + 1024 * 1024, D_, D_);
    k_transpose<<<dim3(32, 32),  256, 0, stream>>>(Wv, WqkvT + 2048 * 1024, D_, D_);
    k_transpose<<<dim3(32, 32),  256, 0, stream>>>(Wo, WoT, D_, D_);
    k_transpose<<<dim3(128, 32), 256, 0, stream>>>(W1, W1T, D_, DFF_);
    k_transpose<<<dim3(32, 128), 256, 0, stream>>>(W2, W2T, DFF_, D_);
    k_bias3<<<12, 256, 0, stream>>>(bq, bk, bv, bqkv);

    k_layernorm<<<M_, 256, 0, stream>>>(x, gpre, bepre, xn);

    k_gemm_bt<0, 1, 0><<<dim3(24, 32), 256, 0, stream>>>(xn, WqkvT, bqkv, nullptr, QKV, M_, QKV_STR, D_);

    k_rope<<<8192, 256, 0, stream>>>(QKV);
    k_vprefix<<<32, 256, 0, stream>>>(QKV + 2048, vpre);

    k_attn_mfma<<<1024, 256, 0, stream>>>(QKV, vpre, att);

    k_gemm64<0, 0, 1><<<dim3(8, 64), 256, 0, stream>>>(att, WoT, bo, x, x2, M_, D_, D_);

    k_layernorm<<<M_, 256, 0, stream>>>(x2, gpost, bepost, x2n);

    k_gemm_bt<1, 1, 0><<<dim3(32, 32), 256, 0, stream>>>(x2n, W1T, b1, nullptr, h1, M_, DFF_, D_);
    k_gemm64<0, 0, 1><<<dim3(8, 64), 256, 0, stream>>>(h1, W2T, b2, x2, (float*)d_out, M_, D_, DFF_);
}

// Round 5
// 345.579 us; speedup vs baseline: 2.5821x; 1.0907x over previous
//
#include <hip/hip_runtime.h>
#include <stdint.h>

#define B_ 2
#define S_ 2048
#define D_ 1024
#define H_ 16
#define HD_ 64
#define DFF_ 4096
#define M_ 4096        // B*S
#define QKV_STR 3072   // fused QKV row stride

typedef float           f4_t  __attribute__((ext_vector_type(4)));
typedef unsigned int    ui4_t __attribute__((ext_vector_type(4)));
typedef unsigned int    ui2_t __attribute__((ext_vector_type(2)));
typedef unsigned short  us4_t __attribute__((ext_vector_type(4)));
typedef unsigned short  us8_t __attribute__((ext_vector_type(8)));
typedef __bf16          bf8_t __attribute__((ext_vector_type(8)));

__device__ __forceinline__ float b2f(unsigned short u) {
    union { unsigned int u; float f; } v; v.u = ((unsigned int)u) << 16; return v.f;
}
__device__ __forceinline__ unsigned short f2b(float f) {
    union { float f; unsigned int u; } v; v.f = f;
    unsigned int u = v.u + 0x7fffu + ((v.u >> 16) & 1u);
    return (unsigned short)(u >> 16);
}
// packed f32x2 -> bf16x2 in one VALU op (lo in [15:0], hi in [31:16])
__device__ __forceinline__ unsigned cvt_pk_bf16(float lo, float hi) {
    unsigned r;
    asm("v_cvt_pk_bf16_f32 %0, %1, %2" : "=v"(r) : "v"(lo), "v"(hi));
    return r;
}
// async global->LDS 16B per lane; lds ptr must be wave-uniform (HW adds lane*16)
__device__ __forceinline__ void gll16(const unsigned short* g, unsigned short* l) {
    __builtin_amdgcn_global_load_lds((const __attribute__((address_space(1))) unsigned int*)g,
                                     (__attribute__((address_space(3))) unsigned int*)l,
                                     16, 0, 0);
}

// ---------------- transpose fp32 [R][C] -> bf16 [C][R] ----------------
__global__ __launch_bounds__(256) void k_transpose(const float* __restrict__ in,
                                                   unsigned short* __restrict__ out,
                                                   int R, int C) {
    __shared__ float tile[32][33];
    const int bc = blockIdx.x * 32, br = blockIdx.y * 32;
    const int tx = threadIdx.x & 31, ty = threadIdx.x >> 5;
#pragma unroll
    for (int i = ty; i < 32; i += 8)
        tile[i][tx] = in[(size_t)(br + i) * C + bc + tx];
    __syncthreads();
#pragma unroll
    for (int i = ty; i < 32; i += 8)
        out[(size_t)(bc + i) * R + br + tx] = f2b(tile[tx][i]);
}

// ---------------- bias concat (bq|bk|bv) ----------------
__global__ __launch_bounds__(256) void k_bias3(const float* __restrict__ a,
                                               const float* __restrict__ b,
                                               const float* __restrict__ c,
                                               float* __restrict__ o) {
    const int t = blockIdx.x * 256 + threadIdx.x;
    if (t < 1024) o[t] = a[t];
    else if (t < 2048) o[t] = b[t - 1024];
    else o[t] = c[t - 2048];
}

// ---------------- layernorm fp32 row(1024) -> bf16 ----------------
__global__ __launch_bounds__(256) void k_layernorm(const float* __restrict__ x,
                                                   const float* __restrict__ g,
                                                   const float* __restrict__ be,
                                                   unsigned short* __restrict__ out) {
    const int row = blockIdx.x;
    const int t = threadIdx.x;
    const float* xr = x + (size_t)row * D_;
    f4_t v = *(const f4_t*)&xr[t * 4];
    float s = v[0] + v[1] + v[2] + v[3];
#pragma unroll
    for (int o = 32; o >= 1; o >>= 1) s += __shfl_down(s, o);
    __shared__ float red[4];
    const int w = t >> 6, lane = t & 63;
    if (lane == 0) red[w] = s;
    __syncthreads();
    const float mean = (red[0] + red[1] + red[2] + red[3]) * (1.f / D_);
    f4_t d;
#pragma unroll
    for (int c = 0; c < 4; c++) d[c] = v[c] - mean;
    float ss = d[0]*d[0] + d[1]*d[1] + d[2]*d[2] + d[3]*d[3];
#pragma unroll
    for (int o = 32; o >= 1; o >>= 1) ss += __shfl_down(ss, o);
    __syncthreads();
    if (lane == 0) red[w] = ss;
    __syncthreads();
    const float var = (red[0] + red[1] + red[2] + red[3]) * (1.f / D_);
    const float rstd = rsqrtf(var + 1e-5f);
    f4_t gv = *(const f4_t*)&g[t * 4];
    f4_t bv = *(const f4_t*)&be[t * 4];
    us4_t o4;
#pragma unroll
    for (int c = 0; c < 4; c++) o4[c] = f2b(d[c] * rstd * gv[c] + bv[c]);
    *(us4_t*)&out[(size_t)row * D_ + t * 4] = o4;
}

// ---------------- bf16 MFMA GEMM 128x128, BK=32, 2-phase dbuf via global_load_lds ----------------
template<int RELU, int BF16OUT, int RESID>
__global__ __launch_bounds__(256) void k_gemm_bt(const unsigned short* __restrict__ A,
                                                 const unsigned short* __restrict__ Bt,
                                                 const float* __restrict__ bias,
                                                 const float* __restrict__ resid,
                                                 void* __restrict__ Cout,
                                                 int M, int N, int K) {
    __shared__ __align__(16) unsigned short As0[128 * 32];
    __shared__ __align__(16) unsigned short Bs0[128 * 32];
    __shared__ __align__(16) unsigned short As1[128 * 32];
    __shared__ __align__(16) unsigned short Bs1[128 * 32];
    const int tid = threadIdx.x;
    const int m0 = blockIdx.y * 128, n0 = blockIdx.x * 128;
    const int w = tid >> 6, lane = tid & 63;
    const int wr = w >> 1, wc = w & 1;
    const int lr = lane & 15, lg = lane >> 4;

    f4_t acc[4][4] = {};

    const int r1 = tid >> 2, q1 = tid & 3;
    const unsigned short* pA1 = A + (size_t)(m0 + r1) * K + q1 * 8;
    const unsigned short* pA2 = pA1 + (size_t)64 * K;
    const unsigned short* pB1 = Bt + (size_t)(n0 + r1) * K + q1 * 8;
    const unsigned short* pB2 = pB1 + (size_t)64 * K;
    const int wofs = w * 512;

#define STAGE(AS, BS, kk) do {                 \
        gll16(pA1 + (kk), (AS) + wofs);        \
        gll16(pA2 + (kk), (AS) + 2048 + wofs); \
        gll16(pB1 + (kk), (BS) + wofs);        \
        gll16(pB2 + (kk), (BS) + 2048 + wofs); } while (0)

#define COMPUTE(AS, BS) do {                                                     \
        bf8_t af[4], bfr[4];                                                     \
        _Pragma("unroll")                                                        \
        for (int f = 0; f < 4; f++) {                                            \
            af[f]  = *(const bf8_t*)&(AS)[(wr * 64 + f * 16 + lr) * 32 + lg * 8];\
            bfr[f] = *(const bf8_t*)&(BS)[(wc * 64 + f * 16 + lr) * 32 + lg * 8];\
        }                                                                        \
        _Pragma("unroll")                                                        \
        for (int mf = 0; mf < 4; mf++)                                           \
            _Pragma("unroll")                                                    \
            for (int nf = 0; nf < 4; nf++)                                       \
                acc[mf][nf] = __builtin_amdgcn_mfma_f32_16x16x32_bf16(           \
                    af[mf], bfr[nf], acc[mf][nf], 0, 0, 0); } while (0)

    // prologue: tile 0 -> buf0
    STAGE(As0, Bs0, 0);
    asm volatile("s_waitcnt vmcnt(0)" ::: "memory");
    __builtin_amdgcn_s_barrier();

    int k0 = 0;
    for (; k0 + 64 < K; k0 += 64) {
        STAGE(As1, Bs1, k0 + 32);   // prefetch while computing buf0
        COMPUTE(As0, Bs0);
        asm volatile("s_waitcnt vmcnt(0)" ::: "memory");
        __builtin_amdgcn_s_barrier();
        STAGE(As0, Bs0, k0 + 64);
        COMPUTE(As1, Bs1);
        asm volatile("s_waitcnt vmcnt(0)" ::: "memory");
        __builtin_amdgcn_s_barrier();
    }
    // two tiles remain: K-64 (in buf0), K-32 (stage now)
    STAGE(As1, Bs1, K - 32);
    COMPUTE(As0, Bs0);
    asm volatile("s_waitcnt vmcnt(0)" ::: "memory");
    __builtin_amdgcn_s_barrier();
    COMPUTE(As1, Bs1);
#undef STAGE
#undef COMPUTE

#pragma unroll
    for (int mf = 0; mf < 4; mf++) {
#pragma unroll
        for (int nf = 0; nf < 4; nf++) {
            const int n = n0 + wc * 64 + nf * 16 + lr;
            const float bv = bias[n];
#pragma unroll
            for (int j = 0; j < 4; j++) {
                const int m = m0 + wr * 64 + mf * 16 + lg * 4 + j;
                float val = acc[mf][nf][j] + bv;
                if (RESID) val += resid[(size_t)m * N + n];
                if (RELU) val = fmaxf(val, 0.f);
                if (BF16OUT) ((unsigned short*)Cout)[(size_t)m * N + n] = f2b(val);
                else         ((float*)Cout)[(size_t)m * N + n] = val;
            }
        }
    }
}

// ---------------- RoPE in-place on fused QKV (Q at col 0, K at col 1024) ----------------
__global__ __launch_bounds__(256) void k_rope(unsigned short* __restrict__ QKV) {
    const int idx = blockIdx.x * 256 + threadIdx.x;
    const int i = idx & 31;
    const int h = (idx >> 5) & 15;
    const int s = (idx >> 9) & 2047;
    const int b = idx >> 20;
    const float freq = exp2f(-(float)i * 0.4152410118609203f);
    const float ang = (float)s * freq;
    float sn, cs;
    sincosf(ang, &sn, &cs);
    const size_t base = ((size_t)(b * S_ + s)) * QKV_STR + h * HD_ + i;
    {
        float a = b2f(QKV[base]), c2 = b2f(QKV[base + 32]);
        QKV[base]      = f2b(a * cs - c2 * sn);
        QKV[base + 32] = f2b(c2 * cs + a * sn);
    }
    {
        float a = b2f(QKV[base + 1024]), c2 = b2f(QKV[base + 1024 + 32]);
        QKV[base + 1024]      = f2b(a * cs - c2 * sn);
        QKV[base + 1024 + 32] = f2b(c2 * cs + a * sn);
    }
}

// ---------------- V chunk column sums: sums[bh][c][d] = colsum of chunk c ----------------
__global__ __launch_bounds__(256) void k_vchunksum(const unsigned short* __restrict__ V,
                                                   float* __restrict__ sums) {
    const int blk = blockIdx.x;          // bh*32 + c
    const int bh = blk >> 5, c = blk & 31;
    const int b = bh >> 4, h = bh & 15;
    const int d = threadIdx.x & 63, r4 = threadIdx.x >> 6;
    const unsigned short* base = V + ((size_t)(b * S_ + c * 64 + r4 * 16)) * QKV_STR + h * HD_ + d;
    float s = 0.f;
#pragma unroll
    for (int r = 0; r < 16; r++) s += b2f(base[(size_t)r * QKV_STR]);
    __shared__ float red[4][64];
    red[r4][d] = s;
    __syncthreads();
    if (r4 == 0) sums[(size_t)blk * 64 + d] = red[0][d] + red[1][d] + red[2][d] + red[3][d];
}

// ---------------- exclusive scan of chunk sums -> pre[bh][33][64] ----------------
__global__ __launch_bounds__(64) void k_vscan(const float* __restrict__ sums,
                                              float* __restrict__ pre) {
    const int bh = blockIdx.x, d = threadIdx.x;
    float cum = 0.f;
    for (int c = 0; c < 32; c++) {
        pre[((size_t)bh * 33 + c) * 64 + d] = cum;
        cum += sums[((size_t)bh * 32 + c) * 64 + d];
    }
    pre[((size_t)bh * 33 + 32) * 64 + d] = cum;
}

// ---------------- MFMA flash attention, register-prefetched staging ----------------
// full-row softmax stats (exp2 domain); causal PV; mask-after-softmax -1e9 term
// via suffix = total - chunkprefix[qblk] - diagonal partial prefix.
#define KS_STRIDE 72   // K tile pad: 64+8

__global__ __launch_bounds__(256) void k_attn_mfma(const unsigned short* __restrict__ QKV,
                                                   const float* __restrict__ vpre,
                                                   unsigned short* __restrict__ Out) {
    __shared__ __align__(16) unsigned short Ks[64 * KS_STRIDE];    // [k][d] padded
    __shared__ __align__(16) unsigned short Vt[64 * 64];           // [d][kv] chunk-swizzled
    __shared__ __align__(16) unsigned short Ps[4][16 * KS_STRIDE]; // per-wave [q][k]

    const int id = blockIdx.x;
    const int wg = (id & 7) * 128 + (id >> 3);   // XCD-chunked bijective swizzle
    const int qblk = 31 - (wg & 31);             // heavy-first for tail balance
    const int bh = wg >> 5;
    const int b = bh >> 4, h = bh & 15;
    const int q0 = qblk * 64;
    const int tid = threadIdx.x;
    const int wq = tid >> 6;
    const int lane = tid & 63;
    const int lr = lane & 15, lg = lane >> 4;
    unsigned short* Pw = Ps[wq];

    const unsigned short* Qp = QKV;
    const unsigned short* Kp = QKV + 1024;
    const unsigned short* Vp = QKV + 2048;

    // Q fragments (B-operand: q = lr, k-dim = d), pre-scaled by (1/8)*log2(e)
    bf8_t qfrag[2];
    {
        const float qs = 0.125f * 1.44269504f;
        const size_t qbase = ((size_t)(b * S_ + q0 + wq * 16 + lr)) * QKV_STR + h * HD_;
#pragma unroll
        for (int ks = 0; ks < 2; ks++) {
            us8_t raw = *(const us8_t*)(Qp + qbase + ks * 32 + lg * 8);
            ui4_t p;
#pragma unroll
            for (int e = 0; e < 4; e++)
                p[e] = cvt_pk_bf16(b2f(raw[e * 2]) * qs, b2f(raw[e * 2 + 1]) * qs);
            union { ui4_t u; bf8_t b; } c; c.u = p;
            qfrag[ks] = c.b;
        }
    }

    // staging geometry: thread handles rows row0 (=tid>>3) and row0+32, col-group g
    const int row0 = tid >> 3, g = tid & 7;
    const int row1 = row0 + 32;
    const int r7 = row0 & 7;
    const int wv = tid >> 6;
    const unsigned short* pK0 = Kp + ((size_t)(b * S_ + row0)) * QKV_STR + h * HD_ + g * 8;
    const unsigned short* pK1 = Kp + ((size_t)(b * S_ + row1)) * QKV_STR + h * HD_ + g * 8;
    const unsigned short* pV0 = Vp + ((size_t)(b * S_ + row0)) * QKV_STR + h * HD_ + g * 8;
    const unsigned short* pV1 = Vp + ((size_t)(b * S_ + row1)) * QKV_STR + h * HD_ + g * 8;

    float m_run = -1e30f, l_run = 0.f;   // in log2 domain
    f4_t acc_o[4] = {};    // O^T: d = dd*16+lg*4+j, q = lr
    f4_t acc_pre[4] = {};  // diagonal partial prefix colsum of V

    const int qb = wq * 16 + lr;

    // prologue: prefetch chunk 0 (qblk >= 0 so V always needed for chunk 0)
    ui4_t ck0 = *(const ui4_t*)pK0;
    ui4_t ck1 = *(const ui4_t*)pK1;
    ui4_t cv0 = *(const ui4_t*)pV0;
    ui4_t cv1 = *(const ui4_t*)pV1;

    for (int kc = 0; kc < 32; kc++) {
        const bool needV = (kc <= qblk);
        __syncthreads();  // prior-chunk LDS reads done
        *(ui4_t*)&Ks[row0 * KS_STRIDE + g * 8] = ck0;
        *(ui4_t*)&Ks[row1 * KS_STRIDE + g * 8] = ck1;
        if (needV) {
            const unsigned short* v0 = (const unsigned short*)&cv0;
            const unsigned short* v1 = (const unsigned short*)&cv1;
            const int sw0 = (wv ^ g) << 3;
            const int sw1 = ((wv + 4) ^ g) << 3;
#pragma unroll
            for (int e = 0; e < 8; e++) {
                const int d = g * 8 + e;
                Vt[d * 64 + sw0 + r7] = v0[e];
                Vt[d * 64 + sw1 + r7] = v1[e];
            }
        }
        // issue next-chunk loads (latency hides under this chunk's compute)
        if (kc < 31) {
            const size_t koff = (size_t)(kc + 1) * 64 * QKV_STR;
            ck0 = *(const ui4_t*)(pK0 + koff);
            ck1 = *(const ui4_t*)(pK1 + koff);
            if (kc + 1 <= qblk) {
                cv0 = *(const ui4_t*)(pV0 + koff);
                cv1 = *(const ui4_t*)(pV1 + koff);
            }
        }
        __syncthreads();

        // S^T = K·Q^T : s4[kk] holds k = kk*16+lg*4+j, q = lr  (log2-domain scores)
        f4_t s4[4] = {};
#pragma unroll
        for (int ks = 0; ks < 2; ks++) {
#pragma unroll
            for (int kk = 0; kk < 4; kk++) {
                bf8_t kf = *(const bf8_t*)&Ks[(kk * 16 + lr) * KS_STRIDE + ks * 32 + lg * 8];
                s4[kk] = __builtin_amdgcn_mfma_f32_16x16x32_bf16(kf, qfrag[ks], s4[kk], 0, 0, 0);
            }
        }

        // online softmax stats over FULL row, defer-max
        float mx = s4[0][0];
#pragma unroll
        for (int kk = 0; kk < 4; kk++)
#pragma unroll
            for (int j = 0; j < 4; j++) mx = fmaxf(mx, s4[kk][j]);
        mx = fmaxf(mx, __shfl_xor(mx, 16));
        mx = fmaxf(mx, __shfl_xor(mx, 32));
        if (!__all(mx <= m_run + 8.f)) {
            const float mnew = fmaxf(m_run, mx);
            const float scl = __builtin_amdgcn_exp2f(m_run - mnew);
            m_run = mnew;
            l_run *= scl;
#pragma unroll
            for (int dd = 0; dd < 4; dd++)
#pragma unroll
                for (int j = 0; j < 4; j++) acc_o[dd][j] *= scl;
        }
        float cs = 0.f;
#pragma unroll
        for (int kk = 0; kk < 4; kk++)
#pragma unroll
            for (int j = 0; j < 4; j++) {
                const float p = __builtin_amdgcn_exp2f(s4[kk][j] - m_run);
                s4[kk][j] = p;
                cs += p;
            }
        cs += __shfl_xor(cs, 16);
        cs += __shfl_xor(cs, 32);
        l_run += cs;

        if (needV) {
            // write P (bf16) masked on diagonal chunk
#pragma unroll
            for (int kk = 0; kk < 4; kk++) {
                const int kb = kk * 16 + lg * 4;
                ui2_t wd;
                if (kc == qblk) {
                    wd[0] = cvt_pk_bf16(kb + 0 <= qb ? s4[kk][0] : 0.f,
                                        kb + 1 <= qb ? s4[kk][1] : 0.f);
                    wd[1] = cvt_pk_bf16(kb + 2 <= qb ? s4[kk][2] : 0.f,
                                        kb + 3 <= qb ? s4[kk][3] : 0.f);
                } else {
                    wd[0] = cvt_pk_bf16(s4[kk][0], s4[kk][1]);
                    wd[1] = cvt_pk_bf16(s4[kk][2], s4[kk][3]);
                }
                *(ui2_t*)&Pw[lr * KS_STRIDE + kk * 16 + lg * 4] = wd;
            }
            // O^T += V^T · P^T  (in-wave LDS write->read)
#pragma unroll
            for (int ks = 0; ks < 2; ks++) {
                bf8_t pf = *(const bf8_t*)&Pw[lr * KS_STRIDE + ks * 32 + lg * 8];
#pragma unroll
                for (int dd = 0; dd < 4; dd++) {
                    bf8_t vf = *(const bf8_t*)&Vt[(dd * 16 + lr) * 64 +
                                                  (((ks * 4 + lg) ^ ((dd * 2 + (lr >> 3)) & 7)) << 3)];
                    acc_o[dd] = __builtin_amdgcn_mfma_f32_16x16x32_bf16(vf, pf, acc_o[dd], 0, 0, 0);
                }
            }
            if (kc == qblk) {
                // diagonal partial prefix: P2[q][k] = (k <= q)
#pragma unroll
                for (int kk = 0; kk < 4; kk++) {
                    const int kb = kk * 16 + lg * 4;
                    ui2_t wd;
                    wd[0] = (kb + 0 <= qb ? 0x3f80u : 0u) | ((kb + 1 <= qb ? 0x3f80u : 0u) << 16);
                    wd[1] = (kb + 2 <= qb ? 0x3f80u : 0u) | ((kb + 3 <= qb ? 0x3f80u : 0u) << 16);
                    *(ui2_t*)&Pw[lr * KS_STRIDE + kk * 16 + lg * 4] = wd;
                }
#pragma unroll
                for (int ks = 0; ks < 2; ks++) {
                    bf8_t pf = *(const bf8_t*)&Pw[lr * KS_STRIDE + ks * 32 + lg * 8];
#pragma unroll
                    for (int dd = 0; dd < 4; dd++) {
                        bf8_t vf = *(const bf8_t*)&Vt[(dd * 16 + lr) * 64 +
                                                      (((ks * 4 + lg) ^ ((dd * 2 + (lr >> 3)) & 7)) << 3)];
                        acc_pre[dd] = __builtin_amdgcn_mfma_f32_16x16x32_bf16(vf, pf, acc_pre[dd], 0, 0, 0);
                    }
                }
            }
        }
    }

    // out = O/l - 1e9 * (total - chunkprefix[qblk] - diag_prefix)
    const float inv_l = 1.f / l_run;
    const float* Cq = vpre + ((size_t)bh * 33 + qblk) * 64;
    const float* Ct = vpre + ((size_t)bh * 33 + 32) * 64;
    const size_t obase = ((size_t)(b * S_ + q0 + wq * 16 + lr)) * D_ + h * HD_;
#pragma unroll
    for (int dd = 0; dd < 4; dd++) {
        const f4_t tq4 = *(const f4_t*)&Cq[dd * 16 + lg * 4];
        const f4_t tt4 = *(const f4_t*)&Ct[dd * 16 + lg * 4];
        float v[4];
#pragma unroll
        for (int j = 0; j < 4; j++)
            v[j] = acc_o[dd][j] * inv_l - 1e9f * (tt4[j] - tq4[j] - acc_pre[dd][j]);
        ui2_t wd;
        wd[0] = cvt_pk_bf16(v[0], v[1]);
        wd[1] = cvt_pk_bf16(v[2], v[3]);
        *(ui2_t*)&Out[obase + dd * 16 + lg * 4] = wd;
    }
}

// ---------------- launch ----------------
extern "C" void kernel_launch(void* const* d_in, const int* in_sizes, int n_in,
                              void* d_out, int out_size, void* d_ws, size_t ws_size,
                              hipStream_t stream) {
    const float* x     = (const float*)d_in[0];
    const float* Wq    = (const float*)d_in[1];  const float* bq = (const float*)d_in[2];
    const float* Wk    = (const float*)d_in[3];  const float* bk = (const float*)d_in[4];
    const float* Wv    = (const float*)d_in[5];  const float* bv = (const float*)d_in[6];
    const float* Wo    = (const float*)d_in[7];  const float* bo = (const float*)d_in[8];
    const float* W1    = (const float*)d_in[9];  const float* b1 = (const float*)d_in[10];
    const float* W2    = (const float*)d_in[11]; const float* b2 = (const float*)d_in[12];
    const float* gpre  = (const float*)d_in[13]; const float* bepre  = (const float*)d_in[14];
    const float* gpost = (const float*)d_in[15]; const float* bepost = (const float*)d_in[16];

    char* ws = (char*)d_ws;
    const size_t MB = 1024 * 1024;
    unsigned short* WqkvT = (unsigned short*)(ws + 0 * MB);    // [3072][1024] bf16, 6MB
    unsigned short* WoT   = (unsigned short*)(ws + 6 * MB);    // 2MB
    unsigned short* W1T   = (unsigned short*)(ws + 8 * MB);    // 8MB
    unsigned short* W2T   = (unsigned short*)(ws + 16 * MB);   // 8MB
    unsigned short* xn    = (unsigned short*)(ws + 24 * MB);   // 8MB
    unsigned short* QKV   = (unsigned short*)(ws + 32 * MB);   // 24MB
    unsigned short* att   = (unsigned short*)(ws + 56 * MB);   // 8MB
    unsigned short* h1    = (unsigned short*)(ws + 24 * MB);   // 32MB (over xn+QKV, dead then)
    unsigned short* x2n   = (unsigned short*)(ws + 56 * MB);   // 8MB (over att, dead then)
    float*          x2    = (float*)(ws + 64 * MB);            // 16MB
    float*          bqkv  = (float*)(ws + 80 * MB);            // 12KB
    float*          vpre  = (float*)(ws + 80 * MB + 16384);    // 270KB
    float*          vsum  = (float*)(ws + 81 * MB);            // 256KB

    k_transpose<<<dim3(32, 32),  256, 0, stream>>>(Wq, WqkvT, D_, D_);
    k_transpose<<<dim3(32, 32),  256, 0, stream>>>(Wk, WqkvT + 1024 * 1024, D_, D_);
    k_transpose<<<dim3(32, 32),  256, 0, stream>>>(Wv, WqkvT + 2048 * 1024, D_, D_);
    k_transpose<<<dim3(32, 32),  256, 0, stream>>>(Wo, WoT, D_, D_);
    k_transpose<<<dim3(128, 32), 256, 0, stream>>>(W1, W1T, D_, DFF_);
    k_transpose<<<dim3(32, 128), 256, 0, stream>>>(W2, W2T, DFF_, D_);
    k_bias3<<<12, 256, 0, stream>>>(bq, bk, bv, bqkv);

    k_layernorm<<<M_, 256, 0, stream>>>(x, gpre, bepre, xn);

    k_gemm_bt<0, 1, 0><<<dim3(24, 32), 256, 0, stream>>>(xn, WqkvT, bqkv, nullptr, QKV, M_, QKV_STR, D_);

    k_rope<<<8192, 256, 0, stream>>>(QKV);
    k_vchunksum<<<1024, 256, 0, stream>>>(QKV + 2048, vsum);
    k_vscan<<<32, 64, 0, stream>>>(vsum, vpre);

    k_attn_mfma<<<1024, 256, 0, stream>>>(QKV, vpre, att);

    k_gemm_bt<0, 0, 1><<<dim3(8, 32), 256, 0, stream>>>(att, WoT, bo, x, x2, M_, D_, D_);

    k_layernorm<<<M_, 256, 0, stream>>>(x2, gpost, bepost, x2n);

    k_gemm_bt<1, 1, 0><<<dim3(32, 32), 256, 0, stream>>>(x2n, W1T, b1, nullptr, h1, M_, DFF_, D_);
    k_gemm_bt<0, 0, 1><<<dim3(8, 32), 256, 0, stream>>>(h1, W2T, b2, x2, (float*)d_out, M_, D_, DFF_);
}